// Round 6
// baseline (429.444 us; speedup 1.0000x reference)
//
#include <hip/hip_runtime.h>
#include <cstdint>
#include <cstddef>

typedef float   f32x4 __attribute__((ext_vector_type(4)));
typedef _Float16 f16x8 __attribute__((ext_vector_type(8)));
typedef _Float16 f16x4 __attribute__((ext_vector_type(4)));

#define TOK  4096   // B*S tokens
#define HID  1024
#define IDIM 4096

// direct global->LDS async copy, 16 B per lane (wave-uniform LDS base + lane*16)
#define GLDS16(gp, lp) __builtin_amdgcn_global_load_lds(                      \
    (const __attribute__((address_space(1))) void*)(gp),                      \
    (__attribute__((address_space(3))) void*)(lp), 16, 0, 0)

// LDS tile layout: 512 slots of 16 B; slot(row,kh) = row*4 + (kh ^ ((row>>1)&3)),
// kh = k-octet (16 B) 0..3. Write side: gload_lds lane l stages row base+(l>>2),
// kh = (l&3)^((l>>3)&3)  -> global reads stay 64B-coalesced per 4 lanes AND the
// ds_read_b128 fragment reads are 2-way-per-bank (free) instead of 8-way.
// (both-sides-or-neither swizzle rule: source perm == read perm.)
//
// Occupancy lesson (R5): grid=256 blocks of 256 thr = 1 blk/CU = 4 waves/CU —
// dead. Small GEMMs keep the 1024-thr 16-wave form (16 waves/CU at 256 blocks).

// ---------------------------------------------------------------------------
// Dense GEMM: 128x128 tile, BK=32, 256 thr = 4 waves (2x2), wave 64x64
// (4x4 MFMA 16x16x32 f16). Split-K over blockIdx.z (1024 blocks = 4 blk/CU).
// ---------------------------------------------------------------------------
__global__ __launch_bounds__(256, 4) void gemm_dense(
    const _Float16* __restrict__ A, const _Float16* __restrict__ B,
    int K, int Kchunk, float* __restrict__ part)
{
    __shared__ _Float16 lA[2][4096];
    __shared__ _Float16 lB[2][4096];
    const int tid  = threadIdx.x;
    const int lane = tid & 63;
    const int wave = tid >> 6;
    const int m0   = blockIdx.x * 128;
    const int n0   = blockIdx.y * 128;
    const int kz0  = blockIdx.z * Kchunk;
    const int wM   = (wave & 1) * 64;
    const int wN   = (wave >> 1) * 64;

    const int srow = lane >> 2;
    const int scol = ((lane & 3) ^ ((lane >> 3) & 3)) * 8;   // swizzled kh
    const _Float16* gA0 = A + (size_t)(m0 + wave * 32 + srow) * K + kz0 + scol;
    const _Float16* gA1 = gA0 + (size_t)16 * K;
    const _Float16* gB0 = B + (size_t)(n0 + wave * 32 + srow) * K + kz0 + scol;
    const _Float16* gB1 = gB0 + (size_t)16 * K;
    const int soff = wave * 1024;

    f32x4 acc[4][4] = {};
    const int fr  = lane & 15;
    const int khr = lane >> 4;
    const int kxo = (khr ^ ((fr >> 1) & 3)) * 8;

    GLDS16(gA0, &lA[0][soff]);
    GLDS16(gA1, &lA[0][soff + 512]);
    GLDS16(gB0, &lB[0][soff]);
    GLDS16(gB1, &lB[0][soff + 512]);
    __syncthreads();

    int cur = 0;
    for (int k = 0; k < Kchunk; k += 32) {
        if (k + 32 < Kchunk) {
            const int nb = cur ^ 1;
            GLDS16(gA0 + k + 32, &lA[nb][soff]);
            GLDS16(gA1 + k + 32, &lA[nb][soff + 512]);
            GLDS16(gB0 + k + 32, &lB[nb][soff]);
            GLDS16(gB1 + k + 32, &lB[nb][soff + 512]);
        }
        f16x8 afr[4], bfr[4];
#pragma unroll
        for (int mi = 0; mi < 4; ++mi)
            afr[mi] = *(const f16x8*)(&lA[cur][(wM + mi * 16 + fr) * 32 + kxo]);
#pragma unroll
        for (int ni = 0; ni < 4; ++ni)
            bfr[ni] = *(const f16x8*)(&lB[cur][(wN + ni * 16 + fr) * 32 + kxo]);
#pragma unroll
        for (int mi = 0; mi < 4; ++mi)
#pragma unroll
            for (int ni = 0; ni < 4; ++ni)
                acc[mi][ni] = __builtin_amdgcn_mfma_f32_16x16x32_f16(
                    afr[mi], bfr[ni], acc[mi][ni], 0, 0, 0);
        __syncthreads();
        cur ^= 1;
    }

    float* dst = part + (size_t)blockIdx.z * TOK * HID;
    const int cn = lane & 15;
    const int rq = (lane >> 4) * 4;
#pragma unroll
    for (int mi = 0; mi < 4; ++mi)
#pragma unroll
        for (int r = 0; r < 4; ++r) {
            const int m = m0 + wM + mi * 16 + rq + r;
#pragma unroll
            for (int ni = 0; ni < 4; ++ni) {
                const int n = n0 + wN + ni * 16 + cn;
                dst[(size_t)m * HID + n] = acc[mi][ni][r];
            }
        }
}

// ---------------------------------------------------------------------------
// Small-K GEMM (R4-measured form): 1024 thr = 16 waves (4x4), wave 32x32
// (2x2 MFMA), 128x128 tile, gload_lds (1 issue/wave/K-step), swizzled LDS,
// 2-phase double-buffer.
// MODE 1: outH = f16(acc + (bias?bias[n]:0))
// MODE 3: outH = f16(acc + addv + sum_t probs*up_b)
// MODE 4: outF = acc + addv
// MODE 5: dual N=512: by<4 -> down=relu(Ah@B^T+bias); by>=4 -> g=A2@B2^T+upb[n]
// ---------------------------------------------------------------------------
template <int MODE>
__global__ __launch_bounds__(1024, 4) void gemm_w32(
    const _Float16* __restrict__ Ah, const _Float16* __restrict__ B,
    int K, int Ncols,
    float* __restrict__ outF, _Float16* __restrict__ outH,
    const float* __restrict__ bias, const float* __restrict__ addv,
    const float* __restrict__ probs, const float* __restrict__ upb,
    const _Float16* __restrict__ A2, const _Float16* __restrict__ B2,
    _Float16* __restrict__ outH2)
{
    __shared__ _Float16 lA[2][4096];
    __shared__ _Float16 lB[2][4096];
    const int tid  = threadIdx.x;
    const int lane = tid & 63;
    const int wave = tid >> 6;
    const int m0   = blockIdx.x * 128;
    int n0, half = 0;
    const _Float16* Ap = Ah;
    const _Float16* Bp = B;
    if constexpr (MODE == 5) {
        half = blockIdx.y >> 2;
        n0 = (blockIdx.y & 3) * 128;
        if (half) { Ap = A2; Bp = B2; }
    } else {
        n0 = blockIdx.y * 128;
    }
    const int wM = (wave & 3) * 32;
    const int wN = (wave >> 2) * 32;

    f32x4 acc[2][2] = {};

    // waves 0-7 stage A rows 16*i8..16*i8+15; waves 8-15 same for B.
    const int i8   = wave & 7;
    const int srow = lane >> 2;
    const int scol = ((lane & 3) ^ ((lane >> 3) & 3)) * 8;
    const _Float16* gsrc = ((wave < 8)
        ? Ap + (size_t)(m0 + i8 * 16 + srow) * K
        : Bp + (size_t)(n0 + i8 * 16 + srow) * K) + scol;
    _Float16* ldst = ((wave < 8) ? &lA[0][0] : &lB[0][0]) + i8 * 512;

    const int fr  = lane & 15;
    const int khr = lane >> 4;
    const int kxo = (khr ^ ((fr >> 1) & 3)) * 8;

    GLDS16(gsrc, ldst);
    __syncthreads();

    int cur = 0;
    for (int k0 = 0; k0 < K; k0 += 32) {
        if (k0 + 32 < K)
            GLDS16(gsrc + k0 + 32, ldst + (cur ^ 1) * 4096);
        f16x8 afr[2], bfr[2];
#pragma unroll
        for (int mi = 0; mi < 2; ++mi)
            afr[mi] = *(const f16x8*)(&lA[cur][(wM + mi * 16 + fr) * 32 + kxo]);
#pragma unroll
        for (int ni = 0; ni < 2; ++ni)
            bfr[ni] = *(const f16x8*)(&lB[cur][(wN + ni * 16 + fr) * 32 + kxo]);
#pragma unroll
        for (int mi = 0; mi < 2; ++mi)
#pragma unroll
            for (int ni = 0; ni < 2; ++ni)
                acc[mi][ni] = __builtin_amdgcn_mfma_f32_16x16x32_f16(
                    afr[mi], bfr[ni], acc[mi][ni], 0, 0, 0);
        __syncthreads();
        cur ^= 1;
    }

    const int cn = lane & 15;
    const int rq = (lane >> 4) * 4;
#pragma unroll
    for (int mi = 0; mi < 2; ++mi)
#pragma unroll
        for (int r = 0; r < 4; ++r) {
            const int m = m0 + wM + mi * 16 + rq + r;
#pragma unroll
            for (int ni = 0; ni < 2; ++ni) {
                const int n = n0 + wN + ni * 16 + cn;
                const float v = acc[mi][ni][r];
                if constexpr (MODE == 1) {
                    const float bb = bias ? bias[n] : 0.f;
                    outH[(size_t)m * Ncols + n] = (_Float16)(v + bb);
                } else if constexpr (MODE == 3) {
                    const size_t idx = (size_t)m * Ncols + n;
                    float s = v + addv[idx];
#pragma unroll
                    for (int t = 0; t < 8; ++t)
                        s += probs[(size_t)m * 8 + t] * upb[t * 1024 + n];
                    outH[idx] = (_Float16)s;
                } else if constexpr (MODE == 4) {
                    const size_t idx = (size_t)m * Ncols + n;
                    outF[idx] = v + addv[idx];
                } else {  // MODE 5
                    const size_t idx = (size_t)m * 512 + n;
                    if (half == 0) {
                        const float y = v + bias[n];
                        outH[idx] = (_Float16)(y > 0.f ? y : 0.f);
                    } else {
                        outH2[idx] = (_Float16)(v + upb[n]);
                    }
                }
            }
        }
}

// ---------------------------------------------------------------------------
// fused split-K reduce + bias + LN: h = sum_z part[z] + dense_b;
// prenorm = h + it; ai = LN(prenorm); emits h_f32, ai(f16), pn(f16)
// ---------------------------------------------------------------------------
__global__ __launch_bounds__(256) void ln_fused(
    const float* __restrict__ part, int sk,
    const float* __restrict__ dbias, const float* __restrict__ it,
    const float* __restrict__ gam, const float* __restrict__ bet,
    float* __restrict__ h_f32, _Float16* __restrict__ ai, _Float16* __restrict__ pn)
{
    const int n = blockIdx.x, tid = threadIdx.x;
    const int lane = tid & 63, wave = tid >> 6;
    const size_t base = (size_t)n * 1024 + tid * 4;
    f32x4 h = *(const f32x4*)(dbias + tid * 4);
    for (int z = 0; z < sk; ++z)
        h += *(const f32x4*)(part + (size_t)z * TOK * HID + base);
    *(f32x4*)(h_f32 + base) = h;
    f32x4 x = h + *(const f32x4*)(it + base);
    float s = x[0] + x[1] + x[2] + x[3];
    float q = x[0] * x[0] + x[1] * x[1] + x[2] * x[2] + x[3] * x[3];
#pragma unroll
    for (int off = 1; off < 64; off <<= 1) {
        s += __shfl_xor(s, off);
        q += __shfl_xor(q, off);
    }
    __shared__ float rs[4], rq[4];
    if (lane == 0) { rs[wave] = s; rq[wave] = q; }
    __syncthreads();
    s = rs[0] + rs[1] + rs[2] + rs[3];
    q = rq[0] + rq[1] + rq[2] + rq[3];
    const float mu = s * (1.f / 1024.f);
    const float var = q * (1.f / 1024.f) - mu * mu;
    const float rstd = rsqrtf(var + 1e-12f);
    f32x4 gv = *(const f32x4*)(gam + tid * 4);
    f32x4 bv = *(const f32x4*)(bet + tid * 4);
    f16x4 av, pv;
#pragma unroll
    for (int j = 0; j < 4; ++j) {
        const float y = (x[j] - mu) * rstd * gv[j] + bv[j];
        av[j] = (_Float16)y;
        pv[j] = (_Float16)x[j];
    }
    *(f16x4*)(ai + base) = av;
    *(f16x4*)(pn + base) = pv;
}

// final LN: out = LN(fuse) where fuse already = input_tensor + fusion
__global__ __launch_bounds__(256) void ln_out(
    const float* __restrict__ fuse, const float* __restrict__ gam,
    const float* __restrict__ bet, float* __restrict__ outp)
{
    const int n = blockIdx.x, tid = threadIdx.x;
    const int lane = tid & 63, wave = tid >> 6;
    const size_t base = (size_t)n * 1024 + tid * 4;
    f32x4 x = *(const f32x4*)(fuse + base);
    float s = x[0] + x[1] + x[2] + x[3];
    float q = x[0] * x[0] + x[1] * x[1] + x[2] * x[2] + x[3] * x[3];
#pragma unroll
    for (int off = 1; off < 64; off <<= 1) {
        s += __shfl_xor(s, off);
        q += __shfl_xor(q, off);
    }
    __shared__ float rs[4], rq[4];
    if (lane == 0) { rs[wave] = s; rq[wave] = q; }
    __syncthreads();
    s = rs[0] + rs[1] + rs[2] + rs[3];
    q = rq[0] + rq[1] + rq[2] + rq[3];
    const float mu = s * (1.f / 1024.f);
    const float var = q * (1.f / 1024.f) - mu * mu;
    const float rstd = rsqrtf(var + 1e-12f);
    f32x4 gv = *(const f32x4*)(gam + tid * 4);
    f32x4 bv = *(const f32x4*)(bet + tid * 4);
    f32x4 y;
#pragma unroll
    for (int j = 0; j < 4; ++j) y[j] = (x[j] - mu) * rstd * gv[j] + bv[j];
    *(f32x4*)(outp + base) = y;
}

// ---------------------------------------------------------------------------
// scores + softmax over T + wdown = probs * down, per token.
// score[t] (up to a t-independent constant) = down.g + pn.WU[t] + cu[t]
// (qk was folded into WU/WG/bg/cu at weight-prep time)
// ---------------------------------------------------------------------------
__global__ __launch_bounds__(256) void scores_softmax(
    const _Float16* __restrict__ pn, const float* __restrict__ WU,
    const float* __restrict__ cu,
    const _Float16* __restrict__ down, const _Float16* __restrict__ g,
    float* __restrict__ probs_out, _Float16* __restrict__ wdown)
{
    const int n = blockIdx.x, tid = threadIdx.x;
    const int lane = tid & 63, wave = tid >> 6;
    const _Float16* pnrow = pn + (size_t)n * 1024;
    float ub[8] = {};
#pragma unroll
    for (int j = 0; j < 4; ++j) {
        const int h = tid + j * 256;
        const float pv = (float)pnrow[h];
#pragma unroll
        for (int t = 0; t < 8; ++t) ub[t] += pv * WU[t * 1024 + h];
    }
#pragma unroll
    for (int off = 1; off < 64; off <<= 1) {
#pragma unroll
        for (int t = 0; t < 8; ++t) ub[t] += __shfl_xor(ub[t], off);
    }
    __shared__ float red[4][9];
    __shared__ float sd[8];
    __shared__ float pl[8];
    if (lane == 0) {
#pragma unroll
        for (int t = 0; t < 8; ++t) red[wave][t] = ub[t];
    }
    const int c0 = tid * 2;
    const size_t dbase = (size_t)n * 512;
    const float d0 = (float)down[dbase + c0];
    const float d1 = (float)down[dbase + c0 + 1];
    float pz = d0 * (float)g[dbase + c0] + d1 * (float)g[dbase + c0 + 1];
#pragma unroll
    for (int off = 1; off < 32; off <<= 1) pz += __shfl_xor(pz, off);
    if ((lane & 31) == 0) sd[wave * 2 + (lane >> 5)] = pz;
    __syncthreads();
    if (tid == 0) {
        float sc[8];
        float mx = -1e30f;
#pragma unroll
        for (int t = 0; t < 8; ++t) {
            sc[t] = sd[t] + cu[t] + red[0][t] + red[1][t] + red[2][t] + red[3][t];
            mx = fmaxf(mx, sc[t]);
        }
        float sum = 0.f;
#pragma unroll
        for (int t = 0; t < 8; ++t) { sc[t] = expf(sc[t] - mx); sum += sc[t]; }
        const float inv = 1.f / sum;
#pragma unroll
        for (int t = 0; t < 8; ++t) pl[t] = sc[t] * inv;
    }
    __syncthreads();
    const float pr = pl[c0 >> 6];
    wdown[dbase + c0]     = (_Float16)(pr * d0);
    wdown[dbase + c0 + 1] = (_Float16)(pr * d1);
    if (tid < 8) probs_out[(size_t)n * 8 + tid] = pl[tid];
}

// ---------------------------------------------------------------------------
// weight-prep helpers
// ---------------------------------------------------------------------------
__device__ inline void cvt_seg(const float* __restrict__ s, _Float16* __restrict__ d,
                               int n4, int gid, int gsz)
{
    for (int i = gid; i < n4; i += gsz) {
        f32x4 v = ((const f32x4*)s)[i];
        f16x4 o;
        o[0] = (_Float16)v[0]; o[1] = (_Float16)v[1];
        o[2] = (_Float16)v[2]; o[3] = (_Float16)v[3];
        ((f16x4*)d)[i] = o;
    }
}

__global__ __launch_bounds__(256) void convert4(
    const float* s0, _Float16* d0, int n0,
    const float* s1, _Float16* d1, int n1,
    const float* s2, _Float16* d2, int n2,
    const float* s3, _Float16* d3, int n3,
    float* bz)   // zero 1024-float accumulator for bfuse
{
    if (blockIdx.x == 0) {
        f32x4 z = {0.f, 0.f, 0.f, 0.f};
        *(f32x4*)(bz + threadIdx.x * 4) = z;
    }
    const int gid = blockIdx.x * 256 + threadIdx.x;
    const int gsz = gridDim.x * 256;
    cvt_seg(s0, d0, n0, gid, gsz);
    cvt_seg(s1, d1, n1, gid, gsz);
    cvt_seg(s2, d2, n2, gid, gsz);
    cvt_seg(s3, d3, n3, gid, gsz);
}

// in [k,h] fp32 -> outp [h,k] f16; optionally rout[h] += sum_k rvec[k]*in[k,h]
__global__ __launch_bounds__(256) void transpose_kw(
    const float* __restrict__ in, _Float16* __restrict__ outp,
    const float* __restrict__ rvec, float* __restrict__ rout)
{
    __shared__ float t[32][33];
    __shared__ float rpart[8][33];
    const int bx = blockIdx.x * 32;   // h
    const int by = blockIdx.y * 32;   // k
    const int tx = threadIdx.x & 31, ty = threadIdx.x >> 5;
#pragma unroll
    for (int j = 0; j < 32; j += 8)
        t[ty + j][tx] = in[(size_t)(by + ty + j) * 1024 + bx + tx];
    __syncthreads();
#pragma unroll
    for (int j = 0; j < 32; j += 8)
        outp[(size_t)(bx + ty + j) * 1024 + by + tx] = (_Float16)t[tx][ty + j];
    if (rvec) {
        float s = 0.f;
#pragma unroll
        for (int j = 0; j < 4; ++j) {
            const int k = ty * 4 + j;
            s += rvec[by + k] * t[k][tx];
        }
        rpart[ty][tx] = s;
        __syncthreads();
        if (ty == 0) {
            float v = rpart[0][tx];
#pragma unroll
            for (int r = 1; r < 8; ++r) v += rpart[r][tx];
            atomicAdd(rout + bx + tx, v);
        }
    }
}

// up_w [t,h,d] -> w_upg[(t*64+d), h]  and  w_upmix[h, t*64+d]   (f16)
__global__ __launch_bounds__(256) void reshape_up(
    const float* __restrict__ up_w, _Float16* __restrict__ upg,
    _Float16* __restrict__ upmix)
{
    const int i = blockIdx.x * 256 + threadIdx.x;
    const int d = i & 63;
    const int h = (i >> 6) & 1023;
    const int t = i >> 16;
    const float v = up_w[i];
    upg[(size_t)(t * 64 + d) * 1024 + h] = (_Float16)v;
    upmix[(size_t)h * 512 + t * 64 + d]  = (_Float16)v;
}

// WU[t,h] = sum_h' WF[h,h']*up_b[t,h'];  bg[td] = sum_h' bfuse[h']*upg[td,h'];
// cu[t] = sum_h' bfuse[h']*up_b[t,h'].   grid: 7 blocks x 256.
__global__ __launch_bounds__(256) void make_score_weights(
    const _Float16* __restrict__ wfuse, const _Float16* __restrict__ upg,
    const float* __restrict__ up_b, const float* __restrict__ bfuse,
    float* __restrict__ WU, float* __restrict__ bg, float* __restrict__ cu)
{
    const int b = blockIdx.x, t = threadIdx.x;
    if (b < 4) {
        const int h = b * 256 + t;
        const _Float16* row = wfuse + (size_t)h * 1024;
        float acc[8] = {};
        for (int hp = 0; hp < 1024; hp += 8) {
            f16x8 w = *(const f16x8*)(row + hp);
#pragma unroll
            for (int j = 0; j < 8; ++j) {
                const float wv = (float)w[j];
#pragma unroll
                for (int tt = 0; tt < 8; ++tt)
                    acc[tt] += wv * up_b[tt * 1024 + hp + j];
            }
        }
#pragma unroll
        for (int tt = 0; tt < 8; ++tt) WU[tt * 1024 + h] = acc[tt];
    } else if (b < 6) {
        const int td = (b - 4) * 256 + t;
        const _Float16* row = upg + (size_t)td * 1024;
        float s = 0.f;
        for (int hp = 0; hp < 1024; hp += 8) {
            f16x8 w = *(const f16x8*)(row + hp);
#pragma unroll
            for (int j = 0; j < 8; ++j) s += (float)w[j] * bfuse[hp + j];
        }
        bg[td] = s;
    } else if (t < 8) {
        float s = 0.f;
        for (int hp = 0; hp < 1024; ++hp) s += bfuse[hp] * up_b[t * 1024 + hp];
        cu[t] = s;
    }
}

// ---------------------------------------------------------------------------
extern "C" void kernel_launch(void* const* d_in, const int* in_sizes, int n_in,
                              void* d_out, int out_size, void* d_ws, size_t ws_size,
                              hipStream_t stream)
{
    const float* hs      = (const float*)d_in[0];
    const float* it      = (const float*)d_in[1];
    const float* dense_w = (const float*)d_in[2];
    const float* dense_b = (const float*)d_in[3];
    const float* ln_g    = (const float*)d_in[4];
    const float* ln_b    = (const float*)d_in[5];
    const float* down_w  = (const float*)d_in[6];
    const float* down_b  = (const float*)d_in[7];
    const float* up_w    = (const float*)d_in[8];
    const float* up_b    = (const float*)d_in[9];
    const float* key_w   = (const float*)d_in[10];
    const float* key_b   = (const float*)d_in[11];
    const float* query_w = (const float*)d_in[12];
    const float* query_b = (const float*)d_in[13];
    const float* value_w = (const float*)d_in[14];
    float* outp = (float*)d_out;
    (void)in_sizes; (void)n_in; (void)out_size; (void)key_b;

    const size_t MiB = 1ull << 20;
    // persistent region (53 MiB)
    char* p = (char*)d_ws;
    _Float16* w_dense  = (_Float16*)p; p += 8 * MiB;
    _Float16* w_queryT = (_Float16*)p; p += 2 * MiB;   // query_w^T [h,q] f16
    _Float16* w_keyT   = (_Float16*)p; p += 2 * MiB;   // key_w^T [h',q] f16
    _Float16* w_value  = (_Float16*)p; p += 2 * MiB;
    _Float16* w_fuseM  = (_Float16*)p; p += 2 * MiB;   // WF[h,h'] row-major f16
    _Float16* w_wg     = (_Float16*)p; p += 1 * MiB;   // WG[td,h] f16 (512x1024)
    _Float16* w_down   = (_Float16*)p; p += 1 * MiB;
    _Float16* w_upg    = (_Float16*)p; p += 1 * MiB;
    _Float16* w_upmix  = (_Float16*)p; p += 1 * MiB;
    float*    bfuse    = (float*)p;    p += 1 * MiB;   // [0..4K) bfuse
    float*    WU       = bfuse + 1024;                 // 32 KB
    float*    bg       = WU + 8 * 1024;                // 2 KB
    float*    cu       = bg + 512;                     // 32 B
    float*    h_f32    = (float*)p;    p += 16 * MiB;
    _Float16* ai       = (_Float16*)p; p += 8 * MiB;   // reused as `mixed`
    _Float16* pn       = (_Float16*)p; p += 8 * MiB;
    // hs_h (32 MiB) aliases h_f32+ai+pn: dead before ln_fused writes them
    _Float16* hs_h = (_Float16*)h_f32;
    // region B: split-K partials first, then (aliased) activations
    char* rb = p;
    const int sk = (ws_size >= (size_t)(53 + 64) * MiB) ? 4 : 2;
    float*    part  = (float*)rb;                 // sk * 16 MiB
    _Float16* down  = (_Float16*)(rb + 16 * MiB); // 4 MiB   (part dead by then)
    _Float16* g     = (_Float16*)(rb + 20 * MiB); // 4 MiB
    _Float16* wdown = (_Float16*)(rb + 24 * MiB); // 4 MiB
    float*    probs = (float*)(rb + 28 * MiB);    // 128 KiB
    float*    fuse  = (float*)rb;                 // 16 MiB (part z0 dead)
    _Float16* mixed = ai;

    // weight prep + hs fp32->f16; zero bfuse (block 0)
    convert4<<<2048, 256, 0, stream>>>(hs, hs_h, TOK * IDIM / 4,
                                       dense_w, w_dense, HID * IDIM / 4,
                                       value_w, w_value, HID * HID / 4,
                                       down_w,  w_down,  512 * HID / 4,
                                       bfuse);
    // w_keyT = key_w^T, and bfuse[h'] = sum_k query_b[k]*key_w[k,h']
    transpose_kw<<<dim3(32, 32), 256, 0, stream>>>(key_w, w_keyT, query_b, bfuse);
    transpose_kw<<<dim3(32, 32), 256, 0, stream>>>(query_w, w_queryT, nullptr, nullptr);
    reshape_up<<<2048, 256, 0, stream>>>(up_w, w_upg, w_upmix);
    // WF[h,h'] = sum_q query_w[q,h]*key_w[q,h']
    gemm_w32<1><<<dim3(8, 8), 1024, 0, stream>>>(
        w_queryT, w_keyT, HID, HID, nullptr, w_fuseM, nullptr, nullptr, nullptr,
        nullptr, nullptr, nullptr, nullptr);
    // WG[td,h] = sum_h' upg[td,h']*WF[h,h']
    gemm_w32<1><<<dim3(4, 8), 1024, 0, stream>>>(
        w_upg, w_fuseM, HID, HID, nullptr, w_wg, nullptr, nullptr, nullptr,
        nullptr, nullptr, nullptr, nullptr);
    // WU, bg, cu
    make_score_weights<<<7, 256, 0, stream>>>(w_fuseM, w_upg, up_b, bfuse,
                                              WU, bg, cu);

    // dense partials: part[z] = hs_h @ dense_w^T  (K chunk per z)
    gemm_dense<<<dim3(32, 8, sk), 256, 0, stream>>>(hs_h, w_dense, IDIM, IDIM / sk, part);
    // h = sum partials + dense_b; ai = LN(h + it); pn = f16(h + it)
    ln_fused<<<TOK, 256, 0, stream>>>(part, sk, dense_b, it, ln_g, ln_b, h_f32, ai, pn);
    // dual: down = relu(ai @ w_down^T + down_b);  g = pn @ w_wg^T + bg
    gemm_w32<5><<<dim3(32, 8), 1024, 0, stream>>>(
        ai, w_down, HID, 512, nullptr, down, down_b, nullptr, nullptr, bg,
        pn, w_wg, g);
    // scores -> softmax over T -> probs, wdown = probs*down
    scores_softmax<<<TOK, 256, 0, stream>>>(pn, WU, cu, down, g, probs, wdown);
    // mixed = wdown @ up_w^T + probs@up_b + h
    gemm_w32<3><<<dim3(32, 8), 1024, 0, stream>>>(
        wdown, w_upmix, 512, HID, nullptr, mixed, nullptr, h_f32, probs, up_b,
        nullptr, nullptr, nullptr);
    // fuse = mixed @ value_w^T + input_tensor
    gemm_w32<4><<<dim3(32, 8), 1024, 0, stream>>>(
        mixed, w_value, HID, HID, fuse, nullptr, nullptr, it, nullptr, nullptr,
        nullptr, nullptr, nullptr);
    // out = LN(fuse)
    ln_out<<<TOK, 256, 0, stream>>>(fuse, ln_g, ln_b, outp);
}

// Round 7
// 350.012 us; speedup vs baseline: 1.2269x; 1.2269x over previous
//
#include <hip/hip_runtime.h>
#include <cstdint>
#include <cstddef>

typedef float   f32x4 __attribute__((ext_vector_type(4)));
typedef _Float16 f16x8 __attribute__((ext_vector_type(8)));
typedef _Float16 f16x4 __attribute__((ext_vector_type(4)));

#define TOK  4096   // B*S tokens
#define HID  1024
#define IDIM 4096

// direct global->LDS async copy, 16 B per lane (wave-uniform LDS base + lane*16)
#define GLDS16(gp, lp) __builtin_amdgcn_global_load_lds(                      \
    (const __attribute__((address_space(1))) void*)(gp),                      \
    (__attribute__((address_space(3))) void*)(lp), 16, 0, 0)

// LDS tile layout: 512 slots of 16 B; slot(row,kh) = row*4 + (kh ^ ((row>>1)&3)),
// kh = k-octet (16 B) 0..3. Write side: gload_lds lane l stages row base+(l>>2),
// kh = (l&3)^((l>>3)&3)  -> global reads stay 64B-coalesced per 4 lanes AND the
// ds_read_b128 fragment reads are 2-way-per-bank (free) instead of 8-way.
// (both-sides-or-neither swizzle rule: source perm == read perm.)
//
// Occupancy lessons: R5 — 256-blk grid of 256 thr = 1 blk/CU = dead; small
// GEMMs stay 1024-thr/16-wave. R6 — 7-blk prep kernel = 77 us at 0.2% occ;
// every kernel must launch >= ~1000 blocks or be provably tiny.

// ---------------------------------------------------------------------------
// Dense GEMM: 128x128 tile, BK=32, 256 thr = 4 waves (2x2), wave 64x64
// (4x4 MFMA 16x16x32 f16). Split-K over blockIdx.z (1024 blocks = 4 blk/CU).
// ---------------------------------------------------------------------------
__global__ __launch_bounds__(256, 4) void gemm_dense(
    const _Float16* __restrict__ A, const _Float16* __restrict__ B,
    int K, int Kchunk, float* __restrict__ part)
{
    __shared__ _Float16 lA[2][4096];
    __shared__ _Float16 lB[2][4096];
    const int tid  = threadIdx.x;
    const int lane = tid & 63;
    const int wave = tid >> 6;
    const int m0   = blockIdx.x * 128;
    const int n0   = blockIdx.y * 128;
    const int kz0  = blockIdx.z * Kchunk;
    const int wM   = (wave & 1) * 64;
    const int wN   = (wave >> 1) * 64;

    const int srow = lane >> 2;
    const int scol = ((lane & 3) ^ ((lane >> 3) & 3)) * 8;   // swizzled kh
    const _Float16* gA0 = A + (size_t)(m0 + wave * 32 + srow) * K + kz0 + scol;
    const _Float16* gA1 = gA0 + (size_t)16 * K;
    const _Float16* gB0 = B + (size_t)(n0 + wave * 32 + srow) * K + kz0 + scol;
    const _Float16* gB1 = gB0 + (size_t)16 * K;
    const int soff = wave * 1024;

    f32x4 acc[4][4] = {};
    const int fr  = lane & 15;
    const int khr = lane >> 4;
    const int kxo = (khr ^ ((fr >> 1) & 3)) * 8;

    GLDS16(gA0, &lA[0][soff]);
    GLDS16(gA1, &lA[0][soff + 512]);
    GLDS16(gB0, &lB[0][soff]);
    GLDS16(gB1, &lB[0][soff + 512]);
    __syncthreads();

    int cur = 0;
    for (int k = 0; k < Kchunk; k += 32) {
        if (k + 32 < Kchunk) {
            const int nb = cur ^ 1;
            GLDS16(gA0 + k + 32, &lA[nb][soff]);
            GLDS16(gA1 + k + 32, &lA[nb][soff + 512]);
            GLDS16(gB0 + k + 32, &lB[nb][soff]);
            GLDS16(gB1 + k + 32, &lB[nb][soff + 512]);
        }
        f16x8 afr[4], bfr[4];
#pragma unroll
        for (int mi = 0; mi < 4; ++mi)
            afr[mi] = *(const f16x8*)(&lA[cur][(wM + mi * 16 + fr) * 32 + kxo]);
#pragma unroll
        for (int ni = 0; ni < 4; ++ni)
            bfr[ni] = *(const f16x8*)(&lB[cur][(wN + ni * 16 + fr) * 32 + kxo]);
#pragma unroll
        for (int mi = 0; mi < 4; ++mi)
#pragma unroll
            for (int ni = 0; ni < 4; ++ni)
                acc[mi][ni] = __builtin_amdgcn_mfma_f32_16x16x32_f16(
                    afr[mi], bfr[ni], acc[mi][ni], 0, 0, 0);
        __syncthreads();
        cur ^= 1;
    }

    float* dst = part + (size_t)blockIdx.z * TOK * HID;
    const int cn = lane & 15;
    const int rq = (lane >> 4) * 4;
#pragma unroll
    for (int mi = 0; mi < 4; ++mi)
#pragma unroll
        for (int r = 0; r < 4; ++r) {
            const int m = m0 + wM + mi * 16 + rq + r;
#pragma unroll
            for (int ni = 0; ni < 4; ++ni) {
                const int n = n0 + wN + ni * 16 + cn;
                dst[(size_t)m * HID + n] = acc[mi][ni][r];
            }
        }
}

// ---------------------------------------------------------------------------
// Small-K GEMM (R4-measured form): 1024 thr = 16 waves (4x4), wave 32x32
// (2x2 MFMA), 128x128 tile, gload_lds (1 issue/wave/K-step), swizzled LDS,
// 2-phase double-buffer.
// MODE 1: outH = f16(acc + (bias?bias[n]:0))
// MODE 3: outH = f16(acc + addv + sum_t probs*up_b)
// MODE 4: outF = acc + addv
// MODE 5: dual N=512: by<4 -> down=relu(Ah@B^T+bias); by>=4 -> g=A2@B2^T+upb[n]
// ---------------------------------------------------------------------------
template <int MODE>
__global__ __launch_bounds__(1024, 4) void gemm_w32(
    const _Float16* __restrict__ Ah, const _Float16* __restrict__ B,
    int K, int Ncols,
    float* __restrict__ outF, _Float16* __restrict__ outH,
    const float* __restrict__ bias, const float* __restrict__ addv,
    const float* __restrict__ probs, const float* __restrict__ upb,
    const _Float16* __restrict__ A2, const _Float16* __restrict__ B2,
    _Float16* __restrict__ outH2)
{
    __shared__ _Float16 lA[2][4096];
    __shared__ _Float16 lB[2][4096];
    const int tid  = threadIdx.x;
    const int lane = tid & 63;
    const int wave = tid >> 6;
    const int m0   = blockIdx.x * 128;
    int n0, half = 0;
    const _Float16* Ap = Ah;
    const _Float16* Bp = B;
    if constexpr (MODE == 5) {
        half = blockIdx.y >> 2;
        n0 = (blockIdx.y & 3) * 128;
        if (half) { Ap = A2; Bp = B2; }
    } else {
        n0 = blockIdx.y * 128;
    }
    const int wM = (wave & 3) * 32;
    const int wN = (wave >> 2) * 32;

    f32x4 acc[2][2] = {};

    // waves 0-7 stage A rows 16*i8..16*i8+15; waves 8-15 same for B.
    const int i8   = wave & 7;
    const int srow = lane >> 2;
    const int scol = ((lane & 3) ^ ((lane >> 3) & 3)) * 8;
    const _Float16* gsrc = ((wave < 8)
        ? Ap + (size_t)(m0 + i8 * 16 + srow) * K
        : Bp + (size_t)(n0 + i8 * 16 + srow) * K) + scol;
    _Float16* ldst = ((wave < 8) ? &lA[0][0] : &lB[0][0]) + i8 * 512;

    const int fr  = lane & 15;
    const int khr = lane >> 4;
    const int kxo = (khr ^ ((fr >> 1) & 3)) * 8;

    GLDS16(gsrc, ldst);
    __syncthreads();

    int cur = 0;
    for (int k0 = 0; k0 < K; k0 += 32) {
        if (k0 + 32 < K)
            GLDS16(gsrc + k0 + 32, ldst + (cur ^ 1) * 4096);
        f16x8 afr[2], bfr[2];
#pragma unroll
        for (int mi = 0; mi < 2; ++mi)
            afr[mi] = *(const f16x8*)(&lA[cur][(wM + mi * 16 + fr) * 32 + kxo]);
#pragma unroll
        for (int ni = 0; ni < 2; ++ni)
            bfr[ni] = *(const f16x8*)(&lB[cur][(wN + ni * 16 + fr) * 32 + kxo]);
#pragma unroll
        for (int mi = 0; mi < 2; ++mi)
#pragma unroll
            for (int ni = 0; ni < 2; ++ni)
                acc[mi][ni] = __builtin_amdgcn_mfma_f32_16x16x32_f16(
                    afr[mi], bfr[ni], acc[mi][ni], 0, 0, 0);
        __syncthreads();
        cur ^= 1;
    }

    const int cn = lane & 15;
    const int rq = (lane >> 4) * 4;
#pragma unroll
    for (int mi = 0; mi < 2; ++mi)
#pragma unroll
        for (int r = 0; r < 4; ++r) {
            const int m = m0 + wM + mi * 16 + rq + r;
#pragma unroll
            for (int ni = 0; ni < 2; ++ni) {
                const int n = n0 + wN + ni * 16 + cn;
                const float v = acc[mi][ni][r];
                if constexpr (MODE == 1) {
                    const float bb = bias ? bias[n] : 0.f;
                    outH[(size_t)m * Ncols + n] = (_Float16)(v + bb);
                } else if constexpr (MODE == 3) {
                    const size_t idx = (size_t)m * Ncols + n;
                    float s = v + addv[idx];
#pragma unroll
                    for (int t = 0; t < 8; ++t)
                        s += probs[(size_t)m * 8 + t] * upb[t * 1024 + n];
                    outH[idx] = (_Float16)s;
                } else if constexpr (MODE == 4) {
                    const size_t idx = (size_t)m * Ncols + n;
                    outF[idx] = v + addv[idx];
                } else {  // MODE 5
                    const size_t idx = (size_t)m * 512 + n;
                    if (half == 0) {
                        const float y = v + bias[n];
                        outH[idx] = (_Float16)(y > 0.f ? y : 0.f);
                    } else {
                        outH2[idx] = (_Float16)(v + upb[n]);
                    }
                }
            }
        }
}

// ---------------------------------------------------------------------------
// fused split-K reduce + bias + LN: h = sum_z part[z] + dense_b;
// prenorm = h + it; ai = LN(prenorm); emits h_f32, ai(f16), pn(f16)
// ---------------------------------------------------------------------------
__global__ __launch_bounds__(256) void ln_fused(
    const float* __restrict__ part, int sk,
    const float* __restrict__ dbias, const float* __restrict__ it,
    const float* __restrict__ gam, const float* __restrict__ bet,
    float* __restrict__ h_f32, _Float16* __restrict__ ai, _Float16* __restrict__ pn)
{
    const int n = blockIdx.x, tid = threadIdx.x;
    const int lane = tid & 63, wave = tid >> 6;
    const size_t base = (size_t)n * 1024 + tid * 4;
    f32x4 h = *(const f32x4*)(dbias + tid * 4);
    for (int z = 0; z < sk; ++z)
        h += *(const f32x4*)(part + (size_t)z * TOK * HID + base);
    *(f32x4*)(h_f32 + base) = h;
    f32x4 x = h + *(const f32x4*)(it + base);
    float s = x[0] + x[1] + x[2] + x[3];
    float q = x[0] * x[0] + x[1] * x[1] + x[2] * x[2] + x[3] * x[3];
#pragma unroll
    for (int off = 1; off < 64; off <<= 1) {
        s += __shfl_xor(s, off);
        q += __shfl_xor(q, off);
    }
    __shared__ float rs[4], rq[4];
    if (lane == 0) { rs[wave] = s; rq[wave] = q; }
    __syncthreads();
    s = rs[0] + rs[1] + rs[2] + rs[3];
    q = rq[0] + rq[1] + rq[2] + rq[3];
    const float mu = s * (1.f / 1024.f);
    const float var = q * (1.f / 1024.f) - mu * mu;
    const float rstd = rsqrtf(var + 1e-12f);
    f32x4 gv = *(const f32x4*)(gam + tid * 4);
    f32x4 bv = *(const f32x4*)(bet + tid * 4);
    f16x4 av, pv;
#pragma unroll
    for (int j = 0; j < 4; ++j) {
        const float y = (x[j] - mu) * rstd * gv[j] + bv[j];
        av[j] = (_Float16)y;
        pv[j] = (_Float16)x[j];
    }
    *(f16x4*)(ai + base) = av;
    *(f16x4*)(pn + base) = pv;
}

// final LN: out = LN(fuse) where fuse already = input_tensor + fusion
__global__ __launch_bounds__(256) void ln_out(
    const float* __restrict__ fuse, const float* __restrict__ gam,
    const float* __restrict__ bet, float* __restrict__ outp)
{
    const int n = blockIdx.x, tid = threadIdx.x;
    const int lane = tid & 63, wave = tid >> 6;
    const size_t base = (size_t)n * 1024 + tid * 4;
    f32x4 x = *(const f32x4*)(fuse + base);
    float s = x[0] + x[1] + x[2] + x[3];
    float q = x[0] * x[0] + x[1] * x[1] + x[2] * x[2] + x[3] * x[3];
#pragma unroll
    for (int off = 1; off < 64; off <<= 1) {
        s += __shfl_xor(s, off);
        q += __shfl_xor(q, off);
    }
    __shared__ float rs[4], rq[4];
    if (lane == 0) { rs[wave] = s; rq[wave] = q; }
    __syncthreads();
    s = rs[0] + rs[1] + rs[2] + rs[3];
    q = rq[0] + rq[1] + rq[2] + rq[3];
    const float mu = s * (1.f / 1024.f);
    const float var = q * (1.f / 1024.f) - mu * mu;
    const float rstd = rsqrtf(var + 1e-12f);
    f32x4 gv = *(const f32x4*)(gam + tid * 4);
    f32x4 bv = *(const f32x4*)(bet + tid * 4);
    f32x4 y;
#pragma unroll
    for (int j = 0; j < 4; ++j) y[j] = (x[j] - mu) * rstd * gv[j] + bv[j];
    *(f32x4*)(outp + base) = y;
}

// ---------------------------------------------------------------------------
// scores + softmax over T + wdown = probs * down, per token.
// score[t] (up to a t-independent constant) = down.g + pn.WU[t] + cu[t]
// ---------------------------------------------------------------------------
__global__ __launch_bounds__(256) void scores_softmax(
    const _Float16* __restrict__ pn, const float* __restrict__ WU,
    const float* __restrict__ cu,
    const _Float16* __restrict__ down, const _Float16* __restrict__ g,
    float* __restrict__ probs_out, _Float16* __restrict__ wdown)
{
    const int n = blockIdx.x, tid = threadIdx.x;
    const int lane = tid & 63, wave = tid >> 6;
    const _Float16* pnrow = pn + (size_t)n * 1024;
    float ub[8] = {};
#pragma unroll
    for (int j = 0; j < 4; ++j) {
        const int h = tid + j * 256;
        const float pv = (float)pnrow[h];
#pragma unroll
        for (int t = 0; t < 8; ++t) ub[t] += pv * WU[t * 1024 + h];
    }
#pragma unroll
    for (int off = 1; off < 64; off <<= 1) {
#pragma unroll
        for (int t = 0; t < 8; ++t) ub[t] += __shfl_xor(ub[t], off);
    }
    __shared__ float red[4][9];
    __shared__ float sd[8];
    __shared__ float pl[8];
    if (lane == 0) {
#pragma unroll
        for (int t = 0; t < 8; ++t) red[wave][t] = ub[t];
    }
    const int c0 = tid * 2;
    const size_t dbase = (size_t)n * 512;
    const float d0 = (float)down[dbase + c0];
    const float d1 = (float)down[dbase + c0 + 1];
    float pz = d0 * (float)g[dbase + c0] + d1 * (float)g[dbase + c0 + 1];
#pragma unroll
    for (int off = 1; off < 32; off <<= 1) pz += __shfl_xor(pz, off);
    if ((lane & 31) == 0) sd[wave * 2 + (lane >> 5)] = pz;
    __syncthreads();
    if (tid == 0) {
        float sc[8];
        float mx = -1e30f;
#pragma unroll
        for (int t = 0; t < 8; ++t) {
            sc[t] = sd[t] + cu[t] + red[0][t] + red[1][t] + red[2][t] + red[3][t];
            mx = fmaxf(mx, sc[t]);
        }
        float sum = 0.f;
#pragma unroll
        for (int t = 0; t < 8; ++t) { sc[t] = expf(sc[t] - mx); sum += sc[t]; }
        const float inv = 1.f / sum;
#pragma unroll
        for (int t = 0; t < 8; ++t) pl[t] = sc[t] * inv;
    }
    __syncthreads();
    const float pr = pl[c0 >> 6];
    wdown[dbase + c0]     = (_Float16)(pr * d0);
    wdown[dbase + c0 + 1] = (_Float16)(pr * d1);
    if (tid < 8) probs_out[(size_t)n * 8 + tid] = pl[tid];
}

// ---------------------------------------------------------------------------
// weight-prep helpers
// ---------------------------------------------------------------------------
__device__ inline void cvt_seg(const float* __restrict__ s, _Float16* __restrict__ d,
                               int n4, int gid, int gsz)
{
    for (int i = gid; i < n4; i += gsz) {
        f32x4 v = ((const f32x4*)s)[i];
        f16x4 o;
        o[0] = (_Float16)v[0]; o[1] = (_Float16)v[1];
        o[2] = (_Float16)v[2]; o[3] = (_Float16)v[3];
        ((f16x4*)d)[i] = o;
    }
}

__global__ __launch_bounds__(256) void convert4(
    const float* s0, _Float16* d0, int n0,
    const float* s1, _Float16* d1, int n1,
    const float* s2, _Float16* d2, int n2,
    const float* s3, _Float16* d3, int n3,
    float* bz)   // zero 1024-float accumulator for bfuse
{
    if (blockIdx.x == 0) {
        f32x4 z = {0.f, 0.f, 0.f, 0.f};
        *(f32x4*)(bz + threadIdx.x * 4) = z;
    }
    const int gid = blockIdx.x * 256 + threadIdx.x;
    const int gsz = gridDim.x * 256;
    cvt_seg(s0, d0, n0, gid, gsz);
    cvt_seg(s1, d1, n1, gid, gsz);
    cvt_seg(s2, d2, n2, gid, gsz);
    cvt_seg(s3, d3, n3, gid, gsz);
}

// in [k,h] fp32 -> outp [h,k] f16; optionally rout[h] += sum_k rvec[k]*in[k,h]
__global__ __launch_bounds__(256) void transpose_kw(
    const float* __restrict__ in, _Float16* __restrict__ outp,
    const float* __restrict__ rvec, float* __restrict__ rout)
{
    __shared__ float t[32][33];
    __shared__ float rpart[8][33];
    const int bx = blockIdx.x * 32;   // h
    const int by = blockIdx.y * 32;   // k
    const int tx = threadIdx.x & 31, ty = threadIdx.x >> 5;
#pragma unroll
    for (int j = 0; j < 32; j += 8)
        t[ty + j][tx] = in[(size_t)(by + ty + j) * 1024 + bx + tx];
    __syncthreads();
#pragma unroll
    for (int j = 0; j < 32; j += 8)
        outp[(size_t)(bx + ty + j) * 1024 + by + tx] = (_Float16)t[tx][ty + j];
    if (rvec) {
        float s = 0.f;
#pragma unroll
        for (int j = 0; j < 4; ++j) {
            const int k = ty * 4 + j;
            s += rvec[by + k] * t[k][tx];
        }
        rpart[ty][tx] = s;
        __syncthreads();
        if (ty == 0) {
            float v = rpart[0][tx];
#pragma unroll
            for (int r = 1; r < 8; ++r) v += rpart[r][tx];
            atomicAdd(rout + bx + tx, v);
        }
    }
}

// up_w [t,h,d] -> w_upg[(t*64+d), h]  and  w_upmix[h, t*64+d]   (f16)
__global__ __launch_bounds__(256) void reshape_up(
    const float* __restrict__ up_w, _Float16* __restrict__ upg,
    _Float16* __restrict__ upmix)
{
    const int i = blockIdx.x * 256 + threadIdx.x;
    const int d = i & 63;
    const int h = (i >> 6) & 1023;
    const int t = i >> 16;
    const float v = up_w[i];
    upg[(size_t)(t * 64 + d) * 1024 + h] = (_Float16)v;
    upmix[(size_t)h * 512 + t * 64 + d]  = (_Float16)v;
}

// score-fold weights, fully parallel (1544 blocks x 256 thr):
//  b<1024:        WU[t][b]  = sum_h' WF[b][h'] * up_b[t][h']   (8 outputs/blk)
//  1024<=b<1536:  bg[b-1024]= sum_h' upg[b-1024][h'] * bfuse[h']
//  1536<=b<1544:  cu[b-1536]= sum_h' bfuse[h'] * up_b[b-1536][h']
__global__ __launch_bounds__(256) void score_weights(
    const _Float16* __restrict__ wfuse, const _Float16* __restrict__ upg,
    const float* __restrict__ up_b, const float* __restrict__ bfuse,
    float* __restrict__ WU, float* __restrict__ bg, float* __restrict__ cu)
{
    const int b = blockIdx.x, tid = threadIdx.x;
    const int lane = tid & 63, wave = tid >> 6;
    __shared__ float red[4][8];
    if (b < 1024) {
        const f16x4 w = *(const f16x4*)(wfuse + (size_t)b * 1024 + tid * 4);
        float a[8] = {};
#pragma unroll
        for (int j = 0; j < 4; ++j) {
            const float wv = (float)w[j];
            const int hp = tid * 4 + j;
#pragma unroll
            for (int t = 0; t < 8; ++t) a[t] += wv * up_b[t * 1024 + hp];
        }
#pragma unroll
        for (int off = 1; off < 64; off <<= 1) {
#pragma unroll
            for (int t = 0; t < 8; ++t) a[t] += __shfl_xor(a[t], off);
        }
        if (lane == 0) {
#pragma unroll
            for (int t = 0; t < 8; ++t) red[wave][t] = a[t];
        }
        __syncthreads();
        if (tid < 8)
            WU[tid * 1024 + b] = red[0][tid] + red[1][tid] + red[2][tid] + red[3][tid];
    } else {
        float s;
        if (b < 1536) {
            const int td = b - 1024;
            const f16x4 w = *(const f16x4*)(upg + (size_t)td * 1024 + tid * 4);
            const f32x4 v = *(const f32x4*)(bfuse + tid * 4);
            s = (float)w[0] * v[0] + (float)w[1] * v[1]
              + (float)w[2] * v[2] + (float)w[3] * v[3];
        } else {
            const int t = b - 1536;
            const f32x4 u = *(const f32x4*)(up_b + (size_t)t * 1024 + tid * 4);
            const f32x4 v = *(const f32x4*)(bfuse + tid * 4);
            s = u[0] * v[0] + u[1] * v[1] + u[2] * v[2] + u[3] * v[3];
        }
#pragma unroll
        for (int off = 1; off < 64; off <<= 1) s += __shfl_xor(s, off);
        if (lane == 0) red[wave][0] = s;
        __syncthreads();
        if (tid == 0) {
            const float tot = red[0][0] + red[1][0] + red[2][0] + red[3][0];
            if (b < 1536) bg[b - 1024] = tot;
            else          cu[b - 1536] = tot;
        }
    }
}

// ---------------------------------------------------------------------------
extern "C" void kernel_launch(void* const* d_in, const int* in_sizes, int n_in,
                              void* d_out, int out_size, void* d_ws, size_t ws_size,
                              hipStream_t stream)
{
    const float* hs      = (const float*)d_in[0];
    const float* it      = (const float*)d_in[1];
    const float* dense_w = (const float*)d_in[2];
    const float* dense_b = (const float*)d_in[3];
    const float* ln_g    = (const float*)d_in[4];
    const float* ln_b    = (const float*)d_in[5];
    const float* down_w  = (const float*)d_in[6];
    const float* down_b  = (const float*)d_in[7];
    const float* up_w    = (const float*)d_in[8];
    const float* up_b    = (const float*)d_in[9];
    const float* key_w   = (const float*)d_in[10];
    const float* key_b   = (const float*)d_in[11];
    const float* query_w = (const float*)d_in[12];
    const float* query_b = (const float*)d_in[13];
    const float* value_w = (const float*)d_in[14];
    float* outp = (float*)d_out;
    (void)in_sizes; (void)n_in; (void)out_size; (void)key_b;

    const size_t MiB = 1ull << 20;
    // persistent region (53 MiB)
    char* p = (char*)d_ws;
    _Float16* w_dense  = (_Float16*)p; p += 8 * MiB;
    _Float16* w_queryT = (_Float16*)p; p += 2 * MiB;   // query_w^T [h,q] f16
    _Float16* w_keyT   = (_Float16*)p; p += 2 * MiB;   // key_w^T [h',q] f16
    _Float16* w_value  = (_Float16*)p; p += 2 * MiB;
    _Float16* w_fuseM  = (_Float16*)p; p += 2 * MiB;   // WF[h,h'] row-major f16
    _Float16* w_wg     = (_Float16*)p; p += 1 * MiB;   // WG[td,h] f16 (512x1024)
    _Float16* w_down   = (_Float16*)p; p += 1 * MiB;
    _Float16* w_upg    = (_Float16*)p; p += 1 * MiB;
    _Float16* w_upmix  = (_Float16*)p; p += 1 * MiB;
    float*    bfuse    = (float*)p;    p += 1 * MiB;   // [0..4K) bfuse
    float*    WU       = bfuse + 1024;                 // 32 KB
    float*    bg       = WU + 8 * 1024;                // 2 KB
    float*    cu       = bg + 512;                     // 32 B
    float*    h_f32    = (float*)p;    p += 16 * MiB;
    _Float16* ai       = (_Float16*)p; p += 8 * MiB;   // reused as `mixed`
    _Float16* pn       = (_Float16*)p; p += 8 * MiB;
    // hs_h (32 MiB) aliases h_f32+ai+pn: dead before ln_fused writes them
    _Float16* hs_h = (_Float16*)h_f32;
    // region B: split-K partials first, then (aliased) activations
    char* rb = p;
    const int sk = (ws_size >= (size_t)(53 + 64) * MiB) ? 4 : 2;
    float*    part  = (float*)rb;                 // sk * 16 MiB
    _Float16* down  = (_Float16*)(rb + 16 * MiB); // 4 MiB   (part dead by then)
    _Float16* g     = (_Float16*)(rb + 20 * MiB); // 4 MiB
    _Float16* wdown = (_Float16*)(rb + 24 * MiB); // 4 MiB
    float*    probs = (float*)(rb + 28 * MiB);    // 128 KiB
    float*    fuse  = (float*)rb;                 // 16 MiB (part z0 dead)
    _Float16* mixed = ai;

    // weight prep + hs fp32->f16; zero bfuse (block 0)
    convert4<<<2048, 256, 0, stream>>>(hs, hs_h, TOK * IDIM / 4,
                                       dense_w, w_dense, HID * IDIM / 4,
                                       value_w, w_value, HID * HID / 4,
                                       down_w,  w_down,  512 * HID / 4,
                                       bfuse);
    // w_keyT = key_w^T, and bfuse[h'] = sum_k query_b[k]*key_w[k,h']
    transpose_kw<<<dim3(32, 32), 256, 0, stream>>>(key_w, w_keyT, query_b, bfuse);
    transpose_kw<<<dim3(32, 32), 256, 0, stream>>>(query_w, w_queryT, nullptr, nullptr);
    reshape_up<<<2048, 256, 0, stream>>>(up_w, w_upg, w_upmix);
    // WF[h,h'] = sum_q query_w[q,h]*key_w[q,h']
    gemm_w32<1><<<dim3(8, 8), 1024, 0, stream>>>(
        w_queryT, w_keyT, HID, HID, nullptr, w_fuseM, nullptr, nullptr, nullptr,
        nullptr, nullptr, nullptr, nullptr);
    // WG[td,h] = sum_h' upg[td,h']*WF[h,h']
    gemm_w32<1><<<dim3(4, 8), 1024, 0, stream>>>(
        w_upg, w_fuseM, HID, HID, nullptr, w_wg, nullptr, nullptr, nullptr,
        nullptr, nullptr, nullptr, nullptr);
    // WU, bg, cu (parallel: 1544 blocks)
    score_weights<<<1544, 256, 0, stream>>>(w_fuseM, w_upg, up_b, bfuse,
                                            WU, bg, cu);

    // dense partials: part[z] = hs_h @ dense_w^T  (K chunk per z)
    gemm_dense<<<dim3(32, 8, sk), 256, 0, stream>>>(hs_h, w_dense, IDIM, IDIM / sk, part);
    // h = sum partials + dense_b; ai = LN(h + it); pn = f16(h + it)
    ln_fused<<<TOK, 256, 0, stream>>>(part, sk, dense_b, it, ln_g, ln_b, h_f32, ai, pn);
    // dual: down = relu(ai @ w_down^T + down_b);  g = pn @ w_wg^T + bg
    gemm_w32<5><<<dim3(32, 8), 1024, 0, stream>>>(
        ai, w_down, HID, 512, nullptr, down, down_b, nullptr, nullptr, bg,
        pn, w_wg, g);
    // scores -> softmax over T -> probs, wdown = probs*down
    scores_softmax<<<TOK, 256, 0, stream>>>(pn, WU, cu, down, g, probs, wdown);
    // mixed = wdown @ up_w^T + probs@up_b + h
    gemm_w32<3><<<dim3(32, 8), 1024, 0, stream>>>(
        wdown, w_upmix, 512, HID, nullptr, mixed, nullptr, h_f32, probs, up_b,
        nullptr, nullptr, nullptr);
    // fuse = mixed @ value_w^T + input_tensor
    gemm_w32<4><<<dim3(32, 8), 1024, 0, stream>>>(
        mixed, w_value, HID, HID, fuse, nullptr, nullptr, it, nullptr, nullptr,
        nullptr, nullptr, nullptr);
    // out = LN(fuse)
    ln_out<<<TOK, 256, 0, stream>>>(fuse, ln_g, ln_b, outp);
}

// Round 9
// 348.594 us; speedup vs baseline: 1.2319x; 1.0041x over previous
//
#include <hip/hip_runtime.h>
#include <cstdint>
#include <cstddef>

typedef float   f32x4 __attribute__((ext_vector_type(4)));
typedef _Float16 f16x8 __attribute__((ext_vector_type(8)));
typedef _Float16 f16x4 __attribute__((ext_vector_type(4)));

#define TOK  4096   // B*S tokens
#define HID  1024
#define IDIM 4096

// direct global->LDS async copy, 16 B per lane (wave-uniform LDS base + lane*16)
#define GLDS16(gp, lp) __builtin_amdgcn_global_load_lds(                      \
    (const __attribute__((address_space(1))) void*)(gp),                      \
    (__attribute__((address_space(3))) void*)(lp), 16, 0, 0)

// LDS tile layout: 512 slots of 16 B; slot(row,kh) = row*4 + (kh ^ ((row>>1)&3)),
// kh = k-octet (16 B) 0..3. Write side: gload_lds lane l stages row base+(l>>2),
// kh = (l&3)^((l>>3)&3)  -> global reads stay 64B-coalesced per 4 lanes AND the
// ds_read_b128 fragment reads are 2-way-per-bank (free) instead of 8-way.
// (both-sides-or-neither swizzle rule: source perm == read perm.)
//
// Occupancy lessons: R5 — 256-blk grid of 256 thr = 1 blk/CU = dead; small
// GEMMs stay 1024-thr/16-wave. R6 — 7-blk prep kernel = 77 us at 0.2% occ.
// R7 — weight-prep GEMMs at 32-64 blocks were ~45 us; ALL GEMMs must reach
// >=256 blocks (use split-K + reduce for small-M shapes).
// R8 — container infra failure; identical kernel resubmitted (static audit ok).

// ---------------------------------------------------------------------------
// Split-K GEMM core: 128x128 tile, BK=32, 256 thr = 4 waves (2x2), wave 64x64
// (4x4 MFMA 16x16x32 f16). Writes fp32 partials at part + z*zstride.
// Output row stride fixed at 1024 (all N=1024 uses).
// ---------------------------------------------------------------------------
__global__ __launch_bounds__(256, 4) void gemm_dense(
    const _Float16* __restrict__ A, const _Float16* __restrict__ B,
    int K, int Kchunk, float* __restrict__ part, size_t zstride)
{
    __shared__ _Float16 lA[2][4096];
    __shared__ _Float16 lB[2][4096];
    const int tid  = threadIdx.x;
    const int lane = tid & 63;
    const int wave = tid >> 6;
    const int m0   = blockIdx.x * 128;
    const int n0   = blockIdx.y * 128;
    const int kz0  = blockIdx.z * Kchunk;
    const int wM   = (wave & 1) * 64;
    const int wN   = (wave >> 1) * 64;

    const int srow = lane >> 2;
    const int scol = ((lane & 3) ^ ((lane >> 3) & 3)) * 8;   // swizzled kh
    const _Float16* gA0 = A + (size_t)(m0 + wave * 32 + srow) * K + kz0 + scol;
    const _Float16* gA1 = gA0 + (size_t)16 * K;
    const _Float16* gB0 = B + (size_t)(n0 + wave * 32 + srow) * K + kz0 + scol;
    const _Float16* gB1 = gB0 + (size_t)16 * K;
    const int soff = wave * 1024;

    f32x4 acc[4][4] = {};
    const int fr  = lane & 15;
    const int khr = lane >> 4;
    const int kxo = (khr ^ ((fr >> 1) & 3)) * 8;

    GLDS16(gA0, &lA[0][soff]);
    GLDS16(gA1, &lA[0][soff + 512]);
    GLDS16(gB0, &lB[0][soff]);
    GLDS16(gB1, &lB[0][soff + 512]);
    __syncthreads();

    int cur = 0;
    for (int k = 0; k < Kchunk; k += 32) {
        if (k + 32 < Kchunk) {
            const int nb = cur ^ 1;
            GLDS16(gA0 + k + 32, &lA[nb][soff]);
            GLDS16(gA1 + k + 32, &lA[nb][soff + 512]);
            GLDS16(gB0 + k + 32, &lB[nb][soff]);
            GLDS16(gB1 + k + 32, &lB[nb][soff + 512]);
        }
        f16x8 afr[4], bfr[4];
#pragma unroll
        for (int mi = 0; mi < 4; ++mi)
            afr[mi] = *(const f16x8*)(&lA[cur][(wM + mi * 16 + fr) * 32 + kxo]);
#pragma unroll
        for (int ni = 0; ni < 4; ++ni)
            bfr[ni] = *(const f16x8*)(&lB[cur][(wN + ni * 16 + fr) * 32 + kxo]);
#pragma unroll
        for (int mi = 0; mi < 4; ++mi)
#pragma unroll
            for (int ni = 0; ni < 4; ++ni)
                acc[mi][ni] = __builtin_amdgcn_mfma_f32_16x16x32_f16(
                    afr[mi], bfr[ni], acc[mi][ni], 0, 0, 0);
        __syncthreads();
        cur ^= 1;
    }

    float* dst = part + (size_t)blockIdx.z * zstride;
    const int cn = lane & 15;
    const int rq = (lane >> 4) * 4;
#pragma unroll
    for (int mi = 0; mi < 4; ++mi)
#pragma unroll
        for (int r = 0; r < 4; ++r) {
            const int m = m0 + wM + mi * 16 + rq + r;
#pragma unroll
            for (int ni = 0; ni < 4; ++ni) {
                const int n = n0 + wN + ni * 16 + cn;
                dst[(size_t)m * HID + n] = acc[mi][ni][r];
            }
        }
}

// out_f16[i] = f16(sum_z in[z*zstride + i]),  n4 = elems/4, grid-stride
__global__ __launch_bounds__(256) void reduce_sk(
    const float* __restrict__ in, size_t zstride4, int sk,
    _Float16* __restrict__ outp, int n4)
{
    const int gid = blockIdx.x * 256 + threadIdx.x;
    const int gsz = gridDim.x * 256;
    for (int i = gid; i < n4; i += gsz) {
        f32x4 v = ((const f32x4*)in)[i];
        for (int z = 1; z < sk; ++z)
            v += ((const f32x4*)in)[z * zstride4 + i];
        f16x4 o;
        o[0] = (_Float16)v[0]; o[1] = (_Float16)v[1];
        o[2] = (_Float16)v[2]; o[3] = (_Float16)v[3];
        ((f16x4*)outp)[i] = o;
    }
}

// ---------------------------------------------------------------------------
// Small-K GEMM (R4-measured form): 1024 thr = 16 waves (4x4), wave 32x32
// (2x2 MFMA), 128x128 tile, gload_lds (1 issue/wave/K-step), swizzled LDS,
// 2-phase double-buffer.
// MODE 3: outH = f16(acc + addv + sum_t probs*up_b)
// MODE 4: outF = acc + addv
// MODE 5: dual N=512: by<4 -> down=relu(Ah@B^T+bias); by>=4 -> g=A2@B2^T+upb[n]
// ---------------------------------------------------------------------------
template <int MODE>
__global__ __launch_bounds__(1024, 4) void gemm_w32(
    const _Float16* __restrict__ Ah, const _Float16* __restrict__ B,
    int K, int Ncols,
    float* __restrict__ outF, _Float16* __restrict__ outH,
    const float* __restrict__ bias, const float* __restrict__ addv,
    const float* __restrict__ probs, const float* __restrict__ upb,
    const _Float16* __restrict__ A2, const _Float16* __restrict__ B2,
    _Float16* __restrict__ outH2)
{
    __shared__ _Float16 lA[2][4096];
    __shared__ _Float16 lB[2][4096];
    const int tid  = threadIdx.x;
    const int lane = tid & 63;
    const int wave = tid >> 6;
    const int m0   = blockIdx.x * 128;
    int n0, half = 0;
    const _Float16* Ap = Ah;
    const _Float16* Bp = B;
    if constexpr (MODE == 5) {
        half = blockIdx.y >> 2;
        n0 = (blockIdx.y & 3) * 128;
        if (half) { Ap = A2; Bp = B2; }
    } else {
        n0 = blockIdx.y * 128;
    }
    const int wM = (wave & 3) * 32;
    const int wN = (wave >> 2) * 32;

    f32x4 acc[2][2] = {};

    // waves 0-7 stage A rows 16*i8..16*i8+15; waves 8-15 same for B.
    const int i8   = wave & 7;
    const int srow = lane >> 2;
    const int scol = ((lane & 3) ^ ((lane >> 3) & 3)) * 8;
    const _Float16* gsrc = ((wave < 8)
        ? Ap + (size_t)(m0 + i8 * 16 + srow) * K
        : Bp + (size_t)(n0 + i8 * 16 + srow) * K) + scol;
    _Float16* ldst = ((wave < 8) ? &lA[0][0] : &lB[0][0]) + i8 * 512;

    const int fr  = lane & 15;
    const int khr = lane >> 4;
    const int kxo = (khr ^ ((fr >> 1) & 3)) * 8;

    GLDS16(gsrc, ldst);
    __syncthreads();

    int cur = 0;
    for (int k0 = 0; k0 < K; k0 += 32) {
        if (k0 + 32 < K)
            GLDS16(gsrc + k0 + 32, ldst + (cur ^ 1) * 4096);
        f16x8 afr[2], bfr[2];
#pragma unroll
        for (int mi = 0; mi < 2; ++mi)
            afr[mi] = *(const f16x8*)(&lA[cur][(wM + mi * 16 + fr) * 32 + kxo]);
#pragma unroll
        for (int ni = 0; ni < 2; ++ni)
            bfr[ni] = *(const f16x8*)(&lB[cur][(wN + ni * 16 + fr) * 32 + kxo]);
#pragma unroll
        for (int mi = 0; mi < 2; ++mi)
#pragma unroll
            for (int ni = 0; ni < 2; ++ni)
                acc[mi][ni] = __builtin_amdgcn_mfma_f32_16x16x32_f16(
                    afr[mi], bfr[ni], acc[mi][ni], 0, 0, 0);
        __syncthreads();
        cur ^= 1;
    }

    const int cn = lane & 15;
    const int rq = (lane >> 4) * 4;
#pragma unroll
    for (int mi = 0; mi < 2; ++mi)
#pragma unroll
        for (int r = 0; r < 4; ++r) {
            const int m = m0 + wM + mi * 16 + rq + r;
#pragma unroll
            for (int ni = 0; ni < 2; ++ni) {
                const int n = n0 + wN + ni * 16 + cn;
                const float v = acc[mi][ni][r];
                if constexpr (MODE == 3) {
                    const size_t idx = (size_t)m * Ncols + n;
                    float s = v + addv[idx];
#pragma unroll
                    for (int t = 0; t < 8; ++t)
                        s += probs[(size_t)m * 8 + t] * upb[t * 1024 + n];
                    outH[idx] = (_Float16)s;
                } else if constexpr (MODE == 4) {
                    const size_t idx = (size_t)m * Ncols + n;
                    outF[idx] = v + addv[idx];
                } else {  // MODE 5
                    const size_t idx = (size_t)m * 512 + n;
                    if (half == 0) {
                        const float y = v + bias[n];
                        outH[idx] = (_Float16)(y > 0.f ? y : 0.f);
                    } else {
                        outH2[idx] = (_Float16)(v + upb[n]);
                    }
                }
            }
        }
}

// ---------------------------------------------------------------------------
// fused split-K reduce + bias + LN: h = sum_z part[z] + dense_b;
// prenorm = h + it; ai = LN(prenorm); emits h_f32, ai(f16), pn(f16)
// ---------------------------------------------------------------------------
__global__ __launch_bounds__(256) void ln_fused(
    const float* __restrict__ part, int sk,
    const float* __restrict__ dbias, const float* __restrict__ it,
    const float* __restrict__ gam, const float* __restrict__ bet,
    float* __restrict__ h_f32, _Float16* __restrict__ ai, _Float16* __restrict__ pn)
{
    const int n = blockIdx.x, tid = threadIdx.x;
    const int lane = tid & 63, wave = tid >> 6;
    const size_t base = (size_t)n * 1024 + tid * 4;
    f32x4 h = *(const f32x4*)(dbias + tid * 4);
    for (int z = 0; z < sk; ++z)
        h += *(const f32x4*)(part + (size_t)z * TOK * HID + base);
    *(f32x4*)(h_f32 + base) = h;
    f32x4 x = h + *(const f32x4*)(it + base);
    float s = x[0] + x[1] + x[2] + x[3];
    float q = x[0] * x[0] + x[1] * x[1] + x[2] * x[2] + x[3] * x[3];
#pragma unroll
    for (int off = 1; off < 64; off <<= 1) {
        s += __shfl_xor(s, off);
        q += __shfl_xor(q, off);
    }
    __shared__ float rs[4], rq[4];
    if (lane == 0) { rs[wave] = s; rq[wave] = q; }
    __syncthreads();
    s = rs[0] + rs[1] + rs[2] + rs[3];
    q = rq[0] + rq[1] + rq[2] + rq[3];
    const float mu = s * (1.f / 1024.f);
    const float var = q * (1.f / 1024.f) - mu * mu;
    const float rstd = rsqrtf(var + 1e-12f);
    f32x4 gv = *(const f32x4*)(gam + tid * 4);
    f32x4 bv = *(const f32x4*)(bet + tid * 4);
    f16x4 av, pv;
#pragma unroll
    for (int j = 0; j < 4; ++j) {
        const float y = (x[j] - mu) * rstd * gv[j] + bv[j];
        av[j] = (_Float16)y;
        pv[j] = (_Float16)x[j];
    }
    *(f16x4*)(ai + base) = av;
    *(f16x4*)(pn + base) = pv;
}

// final LN: out = LN(fuse) where fuse already = input_tensor + fusion
__global__ __launch_bounds__(256) void ln_out(
    const float* __restrict__ fuse, const float* __restrict__ gam,
    const float* __restrict__ bet, float* __restrict__ outp)
{
    const int n = blockIdx.x, tid = threadIdx.x;
    const int lane = tid & 63, wave = tid >> 6;
    const size_t base = (size_t)n * 1024 + tid * 4;
    f32x4 x = *(const f32x4*)(fuse + base);
    float s = x[0] + x[1] + x[2] + x[3];
    float q = x[0] * x[0] + x[1] * x[1] + x[2] * x[2] + x[3] * x[3];
#pragma unroll
    for (int off = 1; off < 64; off <<= 1) {
        s += __shfl_xor(s, off);
        q += __shfl_xor(q, off);
    }
    __shared__ float rs[4], rq[4];
    if (lane == 0) { rs[wave] = s; rq[wave] = q; }
    __syncthreads();
    s = rs[0] + rs[1] + rs[2] + rs[3];
    q = rq[0] + rq[1] + rq[2] + rq[3];
    const float mu = s * (1.f / 1024.f);
    const float var = q * (1.f / 1024.f) - mu * mu;
    const float rstd = rsqrtf(var + 1e-12f);
    f32x4 gv = *(const f32x4*)(gam + tid * 4);
    f32x4 bv = *(const f32x4*)(bet + tid * 4);
    f32x4 y;
#pragma unroll
    for (int j = 0; j < 4; ++j) y[j] = (x[j] - mu) * rstd * gv[j] + bv[j];
    *(f32x4*)(outp + base) = y;
}

// ---------------------------------------------------------------------------
// scores + softmax over T + wdown = probs * down, per token.
// score[t] (up to a t-independent constant) = down.g + pn.WU[t] + cu[t]
// ---------------------------------------------------------------------------
__global__ __launch_bounds__(256) void scores_softmax(
    const _Float16* __restrict__ pn, const float* __restrict__ WU,
    const float* __restrict__ cu,
    const _Float16* __restrict__ down, const _Float16* __restrict__ g,
    float* __restrict__ probs_out, _Float16* __restrict__ wdown)
{
    const int n = blockIdx.x, tid = threadIdx.x;
    const int lane = tid & 63, wave = tid >> 6;
    const _Float16* pnrow = pn + (size_t)n * 1024;
    float ub[8] = {};
#pragma unroll
    for (int j = 0; j < 4; ++j) {
        const int h = tid + j * 256;
        const float pv = (float)pnrow[h];
#pragma unroll
        for (int t = 0; t < 8; ++t) ub[t] += pv * WU[t * 1024 + h];
    }
#pragma unroll
    for (int off = 1; off < 64; off <<= 1) {
#pragma unroll
        for (int t = 0; t < 8; ++t) ub[t] += __shfl_xor(ub[t], off);
    }
    __shared__ float red[4][9];
    __shared__ float sd[8];
    __shared__ float pl[8];
    if (lane == 0) {
#pragma unroll
        for (int t = 0; t < 8; ++t) red[wave][t] = ub[t];
    }
    const int c0 = tid * 2;
    const size_t dbase = (size_t)n * 512;
    const float d0 = (float)down[dbase + c0];
    const float d1 = (float)down[dbase + c0 + 1];
    float pz = d0 * (float)g[dbase + c0] + d1 * (float)g[dbase + c0 + 1];
#pragma unroll
    for (int off = 1; off < 32; off <<= 1) pz += __shfl_xor(pz, off);
    if ((lane & 31) == 0) sd[wave * 2 + (lane >> 5)] = pz;
    __syncthreads();
    if (tid == 0) {
        float sc[8];
        float mx = -1e30f;
#pragma unroll
        for (int t = 0; t < 8; ++t) {
            sc[t] = sd[t] + cu[t] + red[0][t] + red[1][t] + red[2][t] + red[3][t];
            mx = fmaxf(mx, sc[t]);
        }
        float sum = 0.f;
#pragma unroll
        for (int t = 0; t < 8; ++t) { sc[t] = expf(sc[t] - mx); sum += sc[t]; }
        const float inv = 1.f / sum;
#pragma unroll
        for (int t = 0; t < 8; ++t) pl[t] = sc[t] * inv;
    }
    __syncthreads();
    const float pr = pl[c0 >> 6];
    wdown[dbase + c0]     = (_Float16)(pr * d0);
    wdown[dbase + c0 + 1] = (_Float16)(pr * d1);
    if (tid < 8) probs_out[(size_t)n * 8 + tid] = pl[tid];
}

// ---------------------------------------------------------------------------
// weight-prep helpers
// ---------------------------------------------------------------------------
__device__ inline void cvt_seg(const float* __restrict__ s, _Float16* __restrict__ d,
                               int n4, int gid, int gsz)
{
    for (int i = gid; i < n4; i += gsz) {
        f32x4 v = ((const f32x4*)s)[i];
        f16x4 o;
        o[0] = (_Float16)v[0]; o[1] = (_Float16)v[1];
        o[2] = (_Float16)v[2]; o[3] = (_Float16)v[3];
        ((f16x4*)d)[i] = o;
    }
}

__global__ __launch_bounds__(256) void convert4(
    const float* s0, _Float16* d0, int n0,
    const float* s1, _Float16* d1, int n1,
    const float* s2, _Float16* d2, int n2,
    const float* s3, _Float16* d3, int n3,
    float* bz)   // zero 1024-float accumulator for bfuse
{
    if (blockIdx.x == 0) {
        f32x4 z = {0.f, 0.f, 0.f, 0.f};
        *(f32x4*)(bz + threadIdx.x * 4) = z;
    }
    const int gid = blockIdx.x * 256 + threadIdx.x;
    const int gsz = gridDim.x * 256;
    cvt_seg(s0, d0, n0, gid, gsz);
    cvt_seg(s1, d1, n1, gid, gsz);
    cvt_seg(s2, d2, n2, gid, gsz);
    cvt_seg(s3, d3, n3, gid, gsz);
}

// in [k,h] fp32 -> outp [h,k] f16; optionally rout[h] += sum_k rvec[k]*in[k,h]
__global__ __launch_bounds__(256) void transpose_kw(
    const float* __restrict__ in, _Float16* __restrict__ outp,
    const float* __restrict__ rvec, float* __restrict__ rout)
{
    __shared__ float t[32][33];
    __shared__ float rpart[8][33];
    const int bx = blockIdx.x * 32;   // h
    const int by = blockIdx.y * 32;   // k
    const int tx = threadIdx.x & 31, ty = threadIdx.x >> 5;
#pragma unroll
    for (int j = 0; j < 32; j += 8)
        t[ty + j][tx] = in[(size_t)(by + ty + j) * 1024 + bx + tx];
    __syncthreads();
#pragma unroll
    for (int j = 0; j < 32; j += 8)
        outp[(size_t)(bx + ty + j) * 1024 + by + tx] = (_Float16)t[tx][ty + j];
    if (rvec) {
        float s = 0.f;
#pragma unroll
        for (int j = 0; j < 4; ++j) {
            const int k = ty * 4 + j;
            s += rvec[by + k] * t[k][tx];
        }
        rpart[ty][tx] = s;
        __syncthreads();
        if (ty == 0) {
            float v = rpart[0][tx];
#pragma unroll
            for (int r = 1; r < 8; ++r) v += rpart[r][tx];
            atomicAdd(rout + bx + tx, v);
        }
    }
}

// up_w [t,h,d] -> w_upg[(t*64+d), h]  and  w_upmix[h, t*64+d]   (f16)
__global__ __launch_bounds__(256) void reshape_up(
    const float* __restrict__ up_w, _Float16* __restrict__ upg,
    _Float16* __restrict__ upmix)
{
    const int i = blockIdx.x * 256 + threadIdx.x;
    const int d = i & 63;
    const int h = (i >> 6) & 1023;
    const int t = i >> 16;
    const float v = up_w[i];
    upg[(size_t)(t * 64 + d) * 1024 + h] = (_Float16)v;
    upmix[(size_t)h * 512 + t * 64 + d]  = (_Float16)v;
}

// score-fold weights, fully parallel (1544 blocks x 256 thr):
//  b<1024:        WU[t][b]  = sum_h' WF[b][h'] * up_b[t][h']   (8 outputs/blk)
//  1024<=b<1536:  bg[b-1024]= sum_h' upg[b-1024][h'] * bfuse[h']
//  1536<=b<1544:  cu[b-1536]= sum_h' bfuse[h'] * up_b[b-1536][h']
__global__ __launch_bounds__(256) void score_weights(
    const _Float16* __restrict__ wfuse, const _Float16* __restrict__ upg,
    const float* __restrict__ up_b, const float* __restrict__ bfuse,
    float* __restrict__ WU, float* __restrict__ bg, float* __restrict__ cu)
{
    const int b = blockIdx.x, tid = threadIdx.x;
    const int lane = tid & 63, wave = tid >> 6;
    __shared__ float red[4][8];
    if (b < 1024) {
        const f16x4 w = *(const f16x4*)(wfuse + (size_t)b * 1024 + tid * 4);
        float a[8] = {};
#pragma unroll
        for (int j = 0; j < 4; ++j) {
            const float wv = (float)w[j];
            const int hp = tid * 4 + j;
#pragma unroll
            for (int t = 0; t < 8; ++t) a[t] += wv * up_b[t * 1024 + hp];
        }
#pragma unroll
        for (int off = 1; off < 64; off <<= 1) {
#pragma unroll
            for (int t = 0; t < 8; ++t) a[t] += __shfl_xor(a[t], off);
        }
        if (lane == 0) {
#pragma unroll
            for (int t = 0; t < 8; ++t) red[wave][t] = a[t];
        }
        __syncthreads();
        if (tid < 8)
            WU[tid * 1024 + b] = red[0][tid] + red[1][tid] + red[2][tid] + red[3][tid];
    } else {
        float s;
        if (b < 1536) {
            const int td = b - 1024;
            const f16x4 w = *(const f16x4*)(upg + (size_t)td * 1024 + tid * 4);
            const f32x4 v = *(const f32x4*)(bfuse + tid * 4);
            s = (float)w[0] * v[0] + (float)w[1] * v[1]
              + (float)w[2] * v[2] + (float)w[3] * v[3];
        } else {
            const int t = b - 1536;
            const f32x4 u = *(const f32x4*)(up_b + (size_t)t * 1024 + tid * 4);
            const f32x4 v = *(const f32x4*)(bfuse + tid * 4);
            s = u[0] * v[0] + u[1] * v[1] + u[2] * v[2] + u[3] * v[3];
        }
#pragma unroll
        for (int off = 1; off < 64; off <<= 1) s += __shfl_xor(s, off);
        if (lane == 0) red[wave][0] = s;
        __syncthreads();
        if (tid == 0) {
            const float tot = red[0][0] + red[1][0] + red[2][0] + red[3][0];
            if (b < 1536) bg[b - 1024] = tot;
            else          cu[b - 1536] = tot;
        }
    }
}

// ---------------------------------------------------------------------------
extern "C" void kernel_launch(void* const* d_in, const int* in_sizes, int n_in,
                              void* d_out, int out_size, void* d_ws, size_t ws_size,
                              hipStream_t stream)
{
    const float* hs      = (const float*)d_in[0];
    const float* it      = (const float*)d_in[1];
    const float* dense_w = (const float*)d_in[2];
    const float* dense_b = (const float*)d_in[3];
    const float* ln_g    = (const float*)d_in[4];
    const float* ln_b    = (const float*)d_in[5];
    const float* down_w  = (const float*)d_in[6];
    const float* down_b  = (const float*)d_in[7];
    const float* up_w    = (const float*)d_in[8];
    const float* up_b    = (const float*)d_in[9];
    const float* key_w   = (const float*)d_in[10];
    const float* key_b   = (const float*)d_in[11];
    const float* query_w = (const float*)d_in[12];
    const float* query_b = (const float*)d_in[13];
    const float* value_w = (const float*)d_in[14];
    float* outp = (float*)d_out;
    (void)in_sizes; (void)n_in; (void)out_size; (void)key_b;

    const size_t MiB = 1ull << 20;
    // persistent region (53 MiB)
    char* p = (char*)d_ws;
    _Float16* w_dense  = (_Float16*)p; p += 8 * MiB;
    _Float16* w_queryT = (_Float16*)p; p += 2 * MiB;   // query_w^T [h,q] f16
    _Float16* w_keyT   = (_Float16*)p; p += 2 * MiB;   // key_w^T [h',q] f16
    _Float16* w_value  = (_Float16*)p; p += 2 * MiB;
    _Float16* w_fuseM  = (_Float16*)p; p += 2 * MiB;   // WF[h,h'] row-major f16
    _Float16* w_wg     = (_Float16*)p; p += 1 * MiB;   // WG[td,h] f16 (512x1024)
    _Float16* w_down   = (_Float16*)p; p += 1 * MiB;
    _Float16* w_upg    = (_Float16*)p; p += 1 * MiB;
    _Float16* w_upmix  = (_Float16*)p; p += 1 * MiB;
    float*    bfuse    = (float*)p;    p += 1 * MiB;   // [0..4K) bfuse
    float*    WU       = bfuse + 1024;                 // 32 KB
    float*    bg       = WU + 8 * 1024;                // 2 KB
    float*    cu       = bg + 512;                     // 32 B
    float*    h_f32    = (float*)p;    p += 16 * MiB;
    _Float16* ai       = (_Float16*)p; p += 8 * MiB;   // reused as `mixed`
    _Float16* pn       = (_Float16*)p; p += 8 * MiB;
    // hs_h (32 MiB) aliases h_f32+ai+pn: dead before ln_fused writes them
    _Float16* hs_h = (_Float16*)h_f32;
    // region B: prep partials / split-K partials first, then activations
    char* rb = p;
    const int sk = (ws_size >= (size_t)(53 + 64) * MiB) ? 4 : 2;
    float*    prep  = (float*)rb;                 // 16 MiB (dead before part)
    float*    part  = (float*)rb;                 // sk * 16 MiB
    _Float16* down  = (_Float16*)(rb + 16 * MiB); // 4 MiB   (part dead by then)
    _Float16* g     = (_Float16*)(rb + 20 * MiB); // 4 MiB
    _Float16* wdown = (_Float16*)(rb + 24 * MiB); // 4 MiB
    float*    probs = (float*)(rb + 28 * MiB);    // 128 KiB
    float*    fuse  = (float*)rb;                 // 16 MiB (part z0 dead)
    _Float16* mixed = ai;

    // weight prep + hs fp32->f16; zero bfuse (block 0)
    convert4<<<2048, 256, 0, stream>>>(hs, hs_h, TOK * IDIM / 4,
                                       dense_w, w_dense, HID * IDIM / 4,
                                       value_w, w_value, HID * HID / 4,
                                       down_w,  w_down,  512 * HID / 4,
                                       bfuse);
    // w_keyT = key_w^T, and bfuse[h'] = sum_k query_b[k]*key_w[k,h']
    transpose_kw<<<dim3(32, 32), 256, 0, stream>>>(key_w, w_keyT, query_b, bfuse);
    transpose_kw<<<dim3(32, 32), 256, 0, stream>>>(query_w, w_queryT, nullptr, nullptr);
    reshape_up<<<2048, 256, 0, stream>>>(up_w, w_upg, w_upmix);
    // WF[h,h'] = sum_q query_w[q,h]*key_w[q,h']  (split-K x4 for occupancy)
    gemm_dense<<<dim3(8, 8, 4), 256, 0, stream>>>(
        w_queryT, w_keyT, HID, HID / 4, prep, (size_t)HID * HID);
    reduce_sk<<<1024, 256, 0, stream>>>(prep, (size_t)HID * HID / 4, 4,
                                        w_fuseM, HID * HID / 4);
    // WG[td,h] = sum_h' upg[td,h']*WF[h,h']  (split-K x4)
    gemm_dense<<<dim3(4, 8, 4), 256, 0, stream>>>(
        w_upg, w_fuseM, HID, HID / 4, prep, (size_t)512 * HID);
    reduce_sk<<<512, 256, 0, stream>>>(prep, (size_t)512 * HID / 4, 4,
                                       w_wg, 512 * HID / 4);
    // WU, bg, cu (parallel: 1544 blocks)
    score_weights<<<1544, 256, 0, stream>>>(w_fuseM, w_upg, up_b, bfuse,
                                            WU, bg, cu);

    // dense partials: part[z] = hs_h @ dense_w^T  (K chunk per z)
    gemm_dense<<<dim3(32, 8, sk), 256, 0, stream>>>(
        hs_h, w_dense, IDIM, IDIM / sk, part, (size_t)TOK * HID);
    // h = sum partials + dense_b; ai = LN(h + it); pn = f16(h + it)
    ln_fused<<<TOK, 256, 0, stream>>>(part, sk, dense_b, it, ln_g, ln_b, h_f32, ai, pn);
    // dual: down = relu(ai @ w_down^T + down_b);  g = pn @ w_wg^T + bg
    gemm_w32<5><<<dim3(32, 8), 1024, 0, stream>>>(
        ai, w_down, HID, 512, nullptr, down, down_b, nullptr, nullptr, bg,
        pn, w_wg, g);
    // scores -> softmax over T -> probs, wdown = probs*down
    scores_softmax<<<TOK, 256, 0, stream>>>(pn, WU, cu, down, g, probs, wdown);
    // mixed = wdown @ up_w^T + probs@up_b + h
    gemm_w32<3><<<dim3(32, 8), 1024, 0, stream>>>(
        wdown, w_upmix, 512, HID, nullptr, mixed, nullptr, h_f32, probs, up_b,
        nullptr, nullptr, nullptr);
    // fuse = mixed @ value_w^T + input_tensor
    gemm_w32<4><<<dim3(32, 8), 1024, 0, stream>>>(
        mixed, w_value, HID, HID, fuse, nullptr, nullptr, it, nullptr, nullptr,
        nullptr, nullptr, nullptr);
    // out = LN(fuse)
    ln_out<<<TOK, 256, 0, stream>>>(fuse, ln_g, ln_b, outp);
}

// Round 10
// 338.873 us; speedup vs baseline: 1.2673x; 1.0287x over previous
//
#include <hip/hip_runtime.h>
#include <cstdint>
#include <cstddef>

typedef float   f32x4 __attribute__((ext_vector_type(4)));
typedef _Float16 f16x8 __attribute__((ext_vector_type(8)));
typedef _Float16 f16x4 __attribute__((ext_vector_type(4)));

#define TOK  4096   // B*S tokens
#define HID  1024
#define IDIM 4096

// direct global->LDS async copy, 16 B per lane (wave-uniform LDS base + lane*16)
#define GLDS16(gp, lp) __builtin_amdgcn_global_load_lds(                      \
    (const __attribute__((address_space(1))) void*)(gp),                      \
    (__attribute__((address_space(3))) void*)(lp), 16, 0, 0)

// LDS tile layouts (both-sides-or-neither swizzle: source perm == read perm):
//  BK=32 (gemm_dense): slot(row,kh) = row*4 + (kh ^ ((row>>1)&3)), kh 0..3.
//  BK=64 (gemm_w32):   slot(row,kh) = row*8 + (kh ^ (row&7)),      kh 0..7.
// Write side stays linear (gload_lds base+lane*16); the global SOURCE is
// pre-swizzled so coalescing holds (4 or 8 lanes cover one contiguous row
// span, chunk-permuted) and fragment ds_read_b128 is 2-way-per-bank (free).
//
// Occupancy lessons: R5 — 256-blk grid of 256 thr = 1 blk/CU = dead; small
// GEMMs stay 1024-thr/16-wave. R6 — 7-blk prep kernel = 77 us at 0.2% occ.
// R7/R9 — prep GEMMs via split-K gemm_dense (>=128 blks); prep is now noise.
// R10 — gemm_w32 K-step 32->64: 8 MFMA/wave/barrier-pair, half the barriers;
// LDS 64KB is free (grid 256 = 1 blk/CU, thread-limited).

// ---------------------------------------------------------------------------
// Split-K GEMM core: 128x128 tile, BK=32, 256 thr = 4 waves (2x2), wave 64x64
// (4x4 MFMA 16x16x32 f16). Writes fp32 partials at part + z*zstride.
// Output row stride fixed at 1024 (all N=1024 uses).
// ---------------------------------------------------------------------------
__global__ __launch_bounds__(256, 4) void gemm_dense(
    const _Float16* __restrict__ A, const _Float16* __restrict__ B,
    int K, int Kchunk, float* __restrict__ part, size_t zstride)
{
    __shared__ _Float16 lA[2][4096];
    __shared__ _Float16 lB[2][4096];
    const int tid  = threadIdx.x;
    const int lane = tid & 63;
    const int wave = tid >> 6;
    const int m0   = blockIdx.x * 128;
    const int n0   = blockIdx.y * 128;
    const int kz0  = blockIdx.z * Kchunk;
    const int wM   = (wave & 1) * 64;
    const int wN   = (wave >> 1) * 64;

    const int srow = lane >> 2;
    const int scol = ((lane & 3) ^ ((lane >> 3) & 3)) * 8;   // swizzled kh
    const _Float16* gA0 = A + (size_t)(m0 + wave * 32 + srow) * K + kz0 + scol;
    const _Float16* gA1 = gA0 + (size_t)16 * K;
    const _Float16* gB0 = B + (size_t)(n0 + wave * 32 + srow) * K + kz0 + scol;
    const _Float16* gB1 = gB0 + (size_t)16 * K;
    const int soff = wave * 1024;

    f32x4 acc[4][4] = {};
    const int fr  = lane & 15;
    const int khr = lane >> 4;
    const int kxo = (khr ^ ((fr >> 1) & 3)) * 8;

    GLDS16(gA0, &lA[0][soff]);
    GLDS16(gA1, &lA[0][soff + 512]);
    GLDS16(gB0, &lB[0][soff]);
    GLDS16(gB1, &lB[0][soff + 512]);
    __syncthreads();

    int cur = 0;
    for (int k = 0; k < Kchunk; k += 32) {
        if (k + 32 < Kchunk) {
            const int nb = cur ^ 1;
            GLDS16(gA0 + k + 32, &lA[nb][soff]);
            GLDS16(gA1 + k + 32, &lA[nb][soff + 512]);
            GLDS16(gB0 + k + 32, &lB[nb][soff]);
            GLDS16(gB1 + k + 32, &lB[nb][soff + 512]);
        }
        f16x8 afr[4], bfr[4];
#pragma unroll
        for (int mi = 0; mi < 4; ++mi)
            afr[mi] = *(const f16x8*)(&lA[cur][(wM + mi * 16 + fr) * 32 + kxo]);
#pragma unroll
        for (int ni = 0; ni < 4; ++ni)
            bfr[ni] = *(const f16x8*)(&lB[cur][(wN + ni * 16 + fr) * 32 + kxo]);
#pragma unroll
        for (int mi = 0; mi < 4; ++mi)
#pragma unroll
            for (int ni = 0; ni < 4; ++ni)
                acc[mi][ni] = __builtin_amdgcn_mfma_f32_16x16x32_f16(
                    afr[mi], bfr[ni], acc[mi][ni], 0, 0, 0);
        __syncthreads();
        cur ^= 1;
    }

    float* dst = part + (size_t)blockIdx.z * zstride;
    const int cn = lane & 15;
    const int rq = (lane >> 4) * 4;
#pragma unroll
    for (int mi = 0; mi < 4; ++mi)
#pragma unroll
        for (int r = 0; r < 4; ++r) {
            const int m = m0 + wM + mi * 16 + rq + r;
#pragma unroll
            for (int ni = 0; ni < 4; ++ni) {
                const int n = n0 + wN + ni * 16 + cn;
                dst[(size_t)m * HID + n] = acc[mi][ni][r];
            }
        }
}

// out_f16[i] = f16(sum_z in[z*zstride + i]),  n4 = elems/4, grid-stride
__global__ __launch_bounds__(256) void reduce_sk(
    const float* __restrict__ in, size_t zstride4, int sk,
    _Float16* __restrict__ outp, int n4)
{
    const int gid = blockIdx.x * 256 + threadIdx.x;
    const int gsz = gridDim.x * 256;
    for (int i = gid; i < n4; i += gsz) {
        f32x4 v = ((const f32x4*)in)[i];
        for (int z = 1; z < sk; ++z)
            v += ((const f32x4*)in)[z * zstride4 + i];
        f16x4 o;
        o[0] = (_Float16)v[0]; o[1] = (_Float16)v[1];
        o[2] = (_Float16)v[2]; o[3] = (_Float16)v[3];
        ((f16x4*)outp)[i] = o;
    }
}

// ---------------------------------------------------------------------------
// Small-K GEMM: 1024 thr = 16 waves (4x4), wave 32x32 (2x2 MFMA), 128x128
// tile, BK=64: each wave stages 2KB (2x GLDS16), 8 MFMA per barrier-pair,
// swizzled-slot LDS (8 slots/row), 2-phase double-buffer. K must be mult 64.
// MODE 3: outH = f16(acc + addv + sum_t probs*up_b)
// MODE 4: outF = acc + addv
// MODE 5: dual N=512: by<4 -> down=relu(Ah@B^T+bias); by>=4 -> g=A2@B2^T+upb[n]
// ---------------------------------------------------------------------------
template <int MODE>
__global__ __launch_bounds__(1024, 4) void gemm_w32(
    const _Float16* __restrict__ Ah, const _Float16* __restrict__ B,
    int K, int Ncols,
    float* __restrict__ outF, _Float16* __restrict__ outH,
    const float* __restrict__ bias, const float* __restrict__ addv,
    const float* __restrict__ probs, const float* __restrict__ upb,
    const _Float16* __restrict__ A2, const _Float16* __restrict__ B2,
    _Float16* __restrict__ outH2)
{
    __shared__ _Float16 lA[2][8192];
    __shared__ _Float16 lB[2][8192];
    const int tid  = threadIdx.x;
    const int lane = tid & 63;
    const int wave = tid >> 6;
    const int m0   = blockIdx.x * 128;
    int n0, half = 0;
    const _Float16* Ap = Ah;
    const _Float16* Bp = B;
    if constexpr (MODE == 5) {
        half = blockIdx.y >> 2;
        n0 = (blockIdx.y & 3) * 128;
        if (half) { Ap = A2; Bp = B2; }
    } else {
        n0 = blockIdx.y * 128;
    }
    const int wM = (wave & 3) * 32;
    const int wN = (wave >> 2) * 32;

    f32x4 acc[2][2] = {};

    // waves 0-7 stage A rows 16*i8..16*i8+15 (2 issues of 8 rows); 8-15: B.
    const int i8   = wave & 7;
    const int srow = lane >> 3;                              // 0..7
    const int scol = ((lane & 7) ^ ((lane >> 3) & 7)) * 8;   // swizzled kh
    const _Float16* gsrc = ((wave < 8)
        ? Ap + (size_t)(m0 + i8 * 16 + srow) * K
        : Bp + (size_t)(n0 + i8 * 16 + srow) * K) + scol;
    const size_t g8K = (size_t)8 * K;                        // +8 rows
    _Float16* ldst = ((wave < 8) ? &lA[0][0] : &lB[0][0]) + i8 * 1024;

    const int fr  = lane & 15;
    const int khr = lane >> 4;   // 0..3

    GLDS16(gsrc, ldst);
    GLDS16(gsrc + g8K, ldst + 512);
    __syncthreads();

    int cur = 0;
    for (int k0 = 0; k0 < K; k0 += 64) {
        if (k0 + 64 < K) {
            _Float16* nd = ldst + (cur ^ 1) * 8192;
            GLDS16(gsrc + k0 + 64, nd);
            GLDS16(gsrc + k0 + 64 + g8K, nd + 512);
        }
#pragma unroll
        for (int kk = 0; kk < 2; ++kk) {
            f16x8 afr[2], bfr[2];
#pragma unroll
            for (int mi = 0; mi < 2; ++mi) {
                const int row = wM + mi * 16 + fr;
                afr[mi] = *(const f16x8*)(
                    &lA[cur][(row * 8 + ((kk * 4 + khr) ^ (row & 7))) * 8]);
            }
#pragma unroll
            for (int ni = 0; ni < 2; ++ni) {
                const int row = wN + ni * 16 + fr;
                bfr[ni] = *(const f16x8*)(
                    &lB[cur][(row * 8 + ((kk * 4 + khr) ^ (row & 7))) * 8]);
            }
#pragma unroll
            for (int mi = 0; mi < 2; ++mi)
#pragma unroll
                for (int ni = 0; ni < 2; ++ni)
                    acc[mi][ni] = __builtin_amdgcn_mfma_f32_16x16x32_f16(
                        afr[mi], bfr[ni], acc[mi][ni], 0, 0, 0);
        }
        __syncthreads();
        cur ^= 1;
    }

    const int cn = lane & 15;
    const int rq = (lane >> 4) * 4;
#pragma unroll
    for (int mi = 0; mi < 2; ++mi)
#pragma unroll
        for (int r = 0; r < 4; ++r) {
            const int m = m0 + wM + mi * 16 + rq + r;
#pragma unroll
            for (int ni = 0; ni < 2; ++ni) {
                const int n = n0 + wN + ni * 16 + cn;
                const float v = acc[mi][ni][r];
                if constexpr (MODE == 3) {
                    const size_t idx = (size_t)m * Ncols + n;
                    float s = v + addv[idx];
#pragma unroll
                    for (int t = 0; t < 8; ++t)
                        s += probs[(size_t)m * 8 + t] * upb[t * 1024 + n];
                    outH[idx] = (_Float16)s;
                } else if constexpr (MODE == 4) {
                    const size_t idx = (size_t)m * Ncols + n;
                    outF[idx] = v + addv[idx];
                } else {  // MODE 5
                    const size_t idx = (size_t)m * 512 + n;
                    if (half == 0) {
                        const float y = v + bias[n];
                        outH[idx] = (_Float16)(y > 0.f ? y : 0.f);
                    } else {
                        outH2[idx] = (_Float16)(v + upb[n]);
                    }
                }
            }
        }
}

// ---------------------------------------------------------------------------
// fused split-K reduce + bias + LN: h = sum_z part[z] + dense_b;
// prenorm = h + it; ai = LN(prenorm); emits h_f32, ai(f16), pn(f16)
// ---------------------------------------------------------------------------
__global__ __launch_bounds__(256) void ln_fused(
    const float* __restrict__ part, int sk,
    const float* __restrict__ dbias, const float* __restrict__ it,
    const float* __restrict__ gam, const float* __restrict__ bet,
    float* __restrict__ h_f32, _Float16* __restrict__ ai, _Float16* __restrict__ pn)
{
    const int n = blockIdx.x, tid = threadIdx.x;
    const int lane = tid & 63, wave = tid >> 6;
    const size_t base = (size_t)n * 1024 + tid * 4;
    f32x4 h = *(const f32x4*)(dbias + tid * 4);
    for (int z = 0; z < sk; ++z)
        h += *(const f32x4*)(part + (size_t)z * TOK * HID + base);
    *(f32x4*)(h_f32 + base) = h;
    f32x4 x = h + *(const f32x4*)(it + base);
    float s = x[0] + x[1] + x[2] + x[3];
    float q = x[0] * x[0] + x[1] * x[1] + x[2] * x[2] + x[3] * x[3];
#pragma unroll
    for (int off = 1; off < 64; off <<= 1) {
        s += __shfl_xor(s, off);
        q += __shfl_xor(q, off);
    }
    __shared__ float rs[4], rq[4];
    if (lane == 0) { rs[wave] = s; rq[wave] = q; }
    __syncthreads();
    s = rs[0] + rs[1] + rs[2] + rs[3];
    q = rq[0] + rq[1] + rq[2] + rq[3];
    const float mu = s * (1.f / 1024.f);
    const float var = q * (1.f / 1024.f) - mu * mu;
    const float rstd = rsqrtf(var + 1e-12f);
    f32x4 gv = *(const f32x4*)(gam + tid * 4);
    f32x4 bv = *(const f32x4*)(bet + tid * 4);
    f16x4 av, pv;
#pragma unroll
    for (int j = 0; j < 4; ++j) {
        const float y = (x[j] - mu) * rstd * gv[j] + bv[j];
        av[j] = (_Float16)y;
        pv[j] = (_Float16)x[j];
    }
    *(f16x4*)(ai + base) = av;
    *(f16x4*)(pn + base) = pv;
}

// final LN: out = LN(fuse) where fuse already = input_tensor + fusion
__global__ __launch_bounds__(256) void ln_out(
    const float* __restrict__ fuse, const float* __restrict__ gam,
    const float* __restrict__ bet, float* __restrict__ outp)
{
    const int n = blockIdx.x, tid = threadIdx.x;
    const int lane = tid & 63, wave = tid >> 6;
    const size_t base = (size_t)n * 1024 + tid * 4;
    f32x4 x = *(const f32x4*)(fuse + base);
    float s = x[0] + x[1] + x[2] + x[3];
    float q = x[0] * x[0] + x[1] * x[1] + x[2] * x[2] + x[3] * x[3];
#pragma unroll
    for (int off = 1; off < 64; off <<= 1) {
        s += __shfl_xor(s, off);
        q += __shfl_xor(q, off);
    }
    __shared__ float rs[4], rq[4];
    if (lane == 0) { rs[wave] = s; rq[wave] = q; }
    __syncthreads();
    s = rs[0] + rs[1] + rs[2] + rs[3];
    q = rq[0] + rq[1] + rq[2] + rq[3];
    const float mu = s * (1.f / 1024.f);
    const float var = q * (1.f / 1024.f) - mu * mu;
    const float rstd = rsqrtf(var + 1e-12f);
    f32x4 gv = *(const f32x4*)(gam + tid * 4);
    f32x4 bv = *(const f32x4*)(bet + tid * 4);
    f32x4 y;
#pragma unroll
    for (int j = 0; j < 4; ++j) y[j] = (x[j] - mu) * rstd * gv[j] + bv[j];
    *(f32x4*)(outp + base) = y;
}

// ---------------------------------------------------------------------------
// scores + softmax over T + wdown = probs * down, per token.
// score[t] (up to a t-independent constant) = down.g + pn.WU[t] + cu[t]
// ---------------------------------------------------------------------------
__global__ __launch_bounds__(256) void scores_softmax(
    const _Float16* __restrict__ pn, const float* __restrict__ WU,
    const float* __restrict__ cu,
    const _Float16* __restrict__ down, const _Float16* __restrict__ g,
    float* __restrict__ probs_out, _Float16* __restrict__ wdown)
{
    const int n = blockIdx.x, tid = threadIdx.x;
    const int lane = tid & 63, wave = tid >> 6;
    const _Float16* pnrow = pn + (size_t)n * 1024;
    float ub[8] = {};
#pragma unroll
    for (int j = 0; j < 4; ++j) {
        const int h = tid + j * 256;
        const float pv = (float)pnrow[h];
#pragma unroll
        for (int t = 0; t < 8; ++t) ub[t] += pv * WU[t * 1024 + h];
    }
#pragma unroll
    for (int off = 1; off < 64; off <<= 1) {
#pragma unroll
        for (int t = 0; t < 8; ++t) ub[t] += __shfl_xor(ub[t], off);
    }
    __shared__ float red[4][9];
    __shared__ float sd[8];
    __shared__ float pl[8];
    if (lane == 0) {
#pragma unroll
        for (int t = 0; t < 8; ++t) red[wave][t] = ub[t];
    }
    const int c0 = tid * 2;
    const size_t dbase = (size_t)n * 512;
    const float d0 = (float)down[dbase + c0];
    const float d1 = (float)down[dbase + c0 + 1];
    float pz = d0 * (float)g[dbase + c0] + d1 * (float)g[dbase + c0 + 1];
#pragma unroll
    for (int off = 1; off < 32; off <<= 1) pz += __shfl_xor(pz, off);
    if ((lane & 31) == 0) sd[wave * 2 + (lane >> 5)] = pz;
    __syncthreads();
    if (tid == 0) {
        float sc[8];
        float mx = -1e30f;
#pragma unroll
        for (int t = 0; t < 8; ++t) {
            sc[t] = sd[t] + cu[t] + red[0][t] + red[1][t] + red[2][t] + red[3][t];
            mx = fmaxf(mx, sc[t]);
        }
        float sum = 0.f;
#pragma unroll
        for (int t = 0; t < 8; ++t) { sc[t] = expf(sc[t] - mx); sum += sc[t]; }
        const float inv = 1.f / sum;
#pragma unroll
        for (int t = 0; t < 8; ++t) pl[t] = sc[t] * inv;
    }
    __syncthreads();
    const float pr = pl[c0 >> 6];
    wdown[dbase + c0]     = (_Float16)(pr * d0);
    wdown[dbase + c0 + 1] = (_Float16)(pr * d1);
    if (tid < 8) probs_out[(size_t)n * 8 + tid] = pl[tid];
}

// ---------------------------------------------------------------------------
// weight-prep helpers
// ---------------------------------------------------------------------------
__device__ inline void cvt_seg(const float* __restrict__ s, _Float16* __restrict__ d,
                               int n4, int gid, int gsz)
{
    for (int i = gid; i < n4; i += gsz) {
        f32x4 v = ((const f32x4*)s)[i];
        f16x4 o;
        o[0] = (_Float16)v[0]; o[1] = (_Float16)v[1];
        o[2] = (_Float16)v[2]; o[3] = (_Float16)v[3];
        ((f16x4*)d)[i] = o;
    }
}

__global__ __launch_bounds__(256) void convert4(
    const float* s0, _Float16* d0, int n0,
    const float* s1, _Float16* d1, int n1,
    const float* s2, _Float16* d2, int n2,
    const float* s3, _Float16* d3, int n3,
    float* bz)   // zero 1024-float accumulator for bfuse
{
    if (blockIdx.x == 0) {
        f32x4 z = {0.f, 0.f, 0.f, 0.f};
        *(f32x4*)(bz + threadIdx.x * 4) = z;
    }
    const int gid = blockIdx.x * 256 + threadIdx.x;
    const int gsz = gridDim.x * 256;
    cvt_seg(s0, d0, n0, gid, gsz);
    cvt_seg(s1, d1, n1, gid, gsz);
    cvt_seg(s2, d2, n2, gid, gsz);
    cvt_seg(s3, d3, n3, gid, gsz);
}

// in [k,h] fp32 -> outp [h,k] f16; optionally rout[h] += sum_k rvec[k]*in[k,h]
__global__ __launch_bounds__(256) void transpose_kw(
    const float* __restrict__ in, _Float16* __restrict__ outp,
    const float* __restrict__ rvec, float* __restrict__ rout)
{
    __shared__ float t[32][33];
    __shared__ float rpart[8][33];
    const int bx = blockIdx.x * 32;   // h
    const int by = blockIdx.y * 32;   // k
    const int tx = threadIdx.x & 31, ty = threadIdx.x >> 5;
#pragma unroll
    for (int j = 0; j < 32; j += 8)
        t[ty + j][tx] = in[(size_t)(by + ty + j) * 1024 + bx + tx];
    __syncthreads();
#pragma unroll
    for (int j = 0; j < 32; j += 8)
        outp[(size_t)(bx + ty + j) * 1024 + by + tx] = (_Float16)t[tx][ty + j];
    if (rvec) {
        float s = 0.f;
#pragma unroll
        for (int j = 0; j < 4; ++j) {
            const int k = ty * 4 + j;
            s += rvec[by + k] * t[k][tx];
        }
        rpart[ty][tx] = s;
        __syncthreads();
        if (ty == 0) {
            float v = rpart[0][tx];
#pragma unroll
            for (int r = 1; r < 8; ++r) v += rpart[r][tx];
            atomicAdd(rout + bx + tx, v);
        }
    }
}

// up_w [t,h,d] -> w_upg[(t*64+d), h]  and  w_upmix[h, t*64+d]   (f16)
__global__ __launch_bounds__(256) void reshape_up(
    const float* __restrict__ up_w, _Float16* __restrict__ upg,
    _Float16* __restrict__ upmix)
{
    const int i = blockIdx.x * 256 + threadIdx.x;
    const int d = i & 63;
    const int h = (i >> 6) & 1023;
    const int t = i >> 16;
    const float v = up_w[i];
    upg[(size_t)(t * 64 + d) * 1024 + h] = (_Float16)v;
    upmix[(size_t)h * 512 + t * 64 + d]  = (_Float16)v;
}

// score-fold weights, fully parallel (1544 blocks x 256 thr):
//  b<1024:        WU[t][b]  = sum_h' WF[b][h'] * up_b[t][h']   (8 outputs/blk)
//  1024<=b<1536:  bg[b-1024]= sum_h' upg[b-1024][h'] * bfuse[h']
//  1536<=b<1544:  cu[b-1536]= sum_h' bfuse[h'] * up_b[b-1536][h']
__global__ __launch_bounds__(256) void score_weights(
    const _Float16* __restrict__ wfuse, const _Float16* __restrict__ upg,
    const float* __restrict__ up_b, const float* __restrict__ bfuse,
    float* __restrict__ WU, float* __restrict__ bg, float* __restrict__ cu)
{
    const int b = blockIdx.x, tid = threadIdx.x;
    const int lane = tid & 63, wave = tid >> 6;
    __shared__ float red[4][8];
    if (b < 1024) {
        const f16x4 w = *(const f16x4*)(wfuse + (size_t)b * 1024 + tid * 4);
        float a[8] = {};
#pragma unroll
        for (int j = 0; j < 4; ++j) {
            const float wv = (float)w[j];
            const int hp = tid * 4 + j;
#pragma unroll
            for (int t = 0; t < 8; ++t) a[t] += wv * up_b[t * 1024 + hp];
        }
#pragma unroll
        for (int off = 1; off < 64; off <<= 1) {
#pragma unroll
            for (int t = 0; t < 8; ++t) a[t] += __shfl_xor(a[t], off);
        }
        if (lane == 0) {
#pragma unroll
            for (int t = 0; t < 8; ++t) red[wave][t] = a[t];
        }
        __syncthreads();
        if (tid < 8)
            WU[tid * 1024 + b] = red[0][tid] + red[1][tid] + red[2][tid] + red[3][tid];
    } else {
        float s;
        if (b < 1536) {
            const int td = b - 1024;
            const f16x4 w = *(const f16x4*)(upg + (size_t)td * 1024 + tid * 4);
            const f32x4 v = *(const f32x4*)(bfuse + tid * 4);
            s = (float)w[0] * v[0] + (float)w[1] * v[1]
              + (float)w[2] * v[2] + (float)w[3] * v[3];
        } else {
            const int t = b - 1536;
            const f32x4 u = *(const f32x4*)(up_b + (size_t)t * 1024 + tid * 4);
            const f32x4 v = *(const f32x4*)(bfuse + tid * 4);
            s = u[0] * v[0] + u[1] * v[1] + u[2] * v[2] + u[3] * v[3];
        }
#pragma unroll
        for (int off = 1; off < 64; off <<= 1) s += __shfl_xor(s, off);
        if (lane == 0) red[wave][0] = s;
        __syncthreads();
        if (tid == 0) {
            const float tot = red[0][0] + red[1][0] + red[2][0] + red[3][0];
            if (b < 1536) bg[b - 1024] = tot;
            else          cu[b - 1536] = tot;
        }
    }
}

// ---------------------------------------------------------------------------
extern "C" void kernel_launch(void* const* d_in, const int* in_sizes, int n_in,
                              void* d_out, int out_size, void* d_ws, size_t ws_size,
                              hipStream_t stream)
{
    const float* hs      = (const float*)d_in[0];
    const float* it      = (const float*)d_in[1];
    const float* dense_w = (const float*)d_in[2];
    const float* dense_b = (const float*)d_in[3];
    const float* ln_g    = (const float*)d_in[4];
    const float* ln_b    = (const float*)d_in[5];
    const float* down_w  = (const float*)d_in[6];
    const float* down_b  = (const float*)d_in[7];
    const float* up_w    = (const float*)d_in[8];
    const float* up_b    = (const float*)d_in[9];
    const float* key_w   = (const float*)d_in[10];
    const float* key_b   = (const float*)d_in[11];
    const float* query_w = (const float*)d_in[12];
    const float* query_b = (const float*)d_in[13];
    const float* value_w = (const float*)d_in[14];
    float* outp = (float*)d_out;
    (void)in_sizes; (void)n_in; (void)out_size; (void)key_b;

    const size_t MiB = 1ull << 20;
    // persistent region (53 MiB)
    char* p = (char*)d_ws;
    _Float16* w_dense  = (_Float16*)p; p += 8 * MiB;
    _Float16* w_queryT = (_Float16*)p; p += 2 * MiB;   // query_w^T [h,q] f16
    _Float16* w_keyT   = (_Float16*)p; p += 2 * MiB;   // key_w^T [h',q] f16
    _Float16* w_value  = (_Float16*)p; p += 2 * MiB;
    _Float16* w_fuseM  = (_Float16*)p; p += 2 * MiB;   // WF[h,h'] row-major f16
    _Float16* w_wg     = (_Float16*)p; p += 1 * MiB;   // WG[td,h] f16 (512x1024)
    _Float16* w_down   = (_Float16*)p; p += 1 * MiB;
    _Float16* w_upg    = (_Float16*)p; p += 1 * MiB;
    _Float16* w_upmix  = (_Float16*)p; p += 1 * MiB;
    float*    bfuse    = (float*)p;    p += 1 * MiB;   // [0..4K) bfuse
    float*    WU       = bfuse + 1024;                 // 32 KB
    float*    bg       = WU + 8 * 1024;                // 2 KB
    float*    cu       = bg + 512;                     // 32 B
    float*    h_f32    = (float*)p;    p += 16 * MiB;
    _Float16* ai       = (_Float16*)p; p += 8 * MiB;   // reused as `mixed`
    _Float16* pn       = (_Float16*)p; p += 8 * MiB;
    // hs_h (32 MiB) aliases h_f32+ai+pn: dead before ln_fused writes them
    _Float16* hs_h = (_Float16*)h_f32;
    // region B: prep partials / split-K partials first, then activations
    char* rb = p;
    const int sk = (ws_size >= (size_t)(53 + 64) * MiB) ? 4 : 2;
    float*    prep  = (float*)rb;                 // 16 MiB (dead before part)
    float*    part  = (float*)rb;                 // sk * 16 MiB
    _Float16* down  = (_Float16*)(rb + 16 * MiB); // 4 MiB   (part dead by then)
    _Float16* g     = (_Float16*)(rb + 20 * MiB); // 4 MiB
    _Float16* wdown = (_Float16*)(rb + 24 * MiB); // 4 MiB
    float*    probs = (float*)(rb + 28 * MiB);    // 128 KiB
    float*    fuse  = (float*)rb;                 // 16 MiB (part z0 dead)
    _Float16* mixed = ai;

    // weight prep + hs fp32->f16; zero bfuse (block 0)
    convert4<<<2048, 256, 0, stream>>>(hs, hs_h, TOK * IDIM / 4,
                                       dense_w, w_dense, HID * IDIM / 4,
                                       value_w, w_value, HID * HID / 4,
                                       down_w,  w_down,  512 * HID / 4,
                                       bfuse);
    // w_keyT = key_w^T, and bfuse[h'] = sum_k query_b[k]*key_w[k,h']
    transpose_kw<<<dim3(32, 32), 256, 0, stream>>>(key_w, w_keyT, query_b, bfuse);
    transpose_kw<<<dim3(32, 32), 256, 0, stream>>>(query_w, w_queryT, nullptr, nullptr);
    reshape_up<<<2048, 256, 0, stream>>>(up_w, w_upg, w_upmix);
    // WF[h,h'] = sum_q query_w[q,h]*key_w[q,h']  (split-K x4 for occupancy)
    gemm_dense<<<dim3(8, 8, 4), 256, 0, stream>>>(
        w_queryT, w_keyT, HID, HID / 4, prep, (size_t)HID * HID);
    reduce_sk<<<1024, 256, 0, stream>>>(prep, (size_t)HID * HID / 4, 4,
                                        w_fuseM, HID * HID / 4);
    // WG[td,h] = sum_h' upg[td,h']*WF[h,h']  (split-K x4)
    gemm_dense<<<dim3(4, 8, 4), 256, 0, stream>>>(
        w_upg, w_fuseM, HID, HID / 4, prep, (size_t)512 * HID);
    reduce_sk<<<512, 256, 0, stream>>>(prep, (size_t)512 * HID / 4, 4,
                                       w_wg, 512 * HID / 4);
    // WU, bg, cu (parallel: 1544 blocks)
    score_weights<<<1544, 256, 0, stream>>>(w_fuseM, w_upg, up_b, bfuse,
                                            WU, bg, cu);

    // dense partials: part[z] = hs_h @ dense_w^T  (K chunk per z)
    gemm_dense<<<dim3(32, 8, sk), 256, 0, stream>>>(
        hs_h, w_dense, IDIM, IDIM / sk, part, (size_t)TOK * HID);
    // h = sum partials + dense_b; ai = LN(h + it); pn = f16(h + it)
    ln_fused<<<TOK, 256, 0, stream>>>(part, sk, dense_b, it, ln_g, ln_b, h_f32, ai, pn);
    // dual: down = relu(ai @ w_down^T + down_b);  g = pn @ w_wg^T + bg
    gemm_w32<5><<<dim3(32, 8), 1024, 0, stream>>>(
        ai, w_down, HID, 512, nullptr, down, down_b, nullptr, nullptr, bg,
        pn, w_wg, g);
    // scores -> softmax over T -> probs, wdown = probs*down
    scores_softmax<<<TOK, 256, 0, stream>>>(pn, WU, cu, down, g, probs, wdown);
    // mixed = wdown @ up_w^T + probs@up_b + h
    gemm_w32<3><<<dim3(32, 8), 1024, 0, stream>>>(
        wdown, w_upmix, 512, HID, nullptr, mixed, nullptr, h_f32, probs, up_b,
        nullptr, nullptr, nullptr);
    // fuse = mixed @ value_w^T + input_tensor
    gemm_w32<4><<<dim3(32, 8), 1024, 0, stream>>>(
        mixed, w_value, HID, HID, fuse, nullptr, nullptr, it, nullptr, nullptr,
        nullptr, nullptr, nullptr);
    // out = LN(fuse)
    ln_out<<<TOK, 256, 0, stream>>>(fuse, ln_g, ln_b, outp);
}